// Round 15
// baseline (1142.209 us; speedup 1.0000x reference)
//
#include <hip/hip_runtime.h>
#include <hip/hip_bf16.h>
#include <hip/hip_fp16.h>
#include <math.h>

// ---------- constants ----------
#define BB 4
#define FBINS 196
#define TT 1000
#define DM 512
#define HH 8
#define DEPTH 64
#define FFN 2048
#define LL 4
#define EDIM 128
#define BT (BB*TT)   // 4000
#define PSHIFT 12.0f

typedef __hip_bfloat16 bf16;
typedef __attribute__((ext_vector_type(8))) short short8;
typedef __attribute__((ext_vector_type(4))) float floatx4;

// ---------- private arena ----------
#define ARENA_BYTES 420000000ULL
static void* g_arena = nullptr;
__attribute__((constructor)) static void arena_init() {
    if (!g_arena) (void)hipMalloc(&g_arena, ARENA_BYTES);
}

__device__ __forceinline__ float gelu_f(float x) {
    return 0.5f * x * (1.0f + erff(x * 0.70710678118654752440f));
}
// gelu is valley-shaped (decreasing then increasing, min at x~-0.7518), so
// max_i gelu(x_i) == max(gelu(min_i x_i), gelu(max_i x_i)) EXACTLY.

// ---------- dtype sniffer (cnt==0 <=> inputs are bf16) ----------
__global__ __launch_bounds__(256) void sniff_k(const unsigned short* __restrict__ p,
                                               int n, int* __restrict__ cnt) {
    int i = blockIdx.x * 256 + threadIdx.x;
    int c = 0;
    for (; i < n; i += gridDim.x * 256) {
        unsigned short u = p[i];
        if ((unsigned short)(u & 0x7FFF) > (unsigned short)0x7F80) c++;
    }
    if (c) atomicAdd(cnt, c);
}

// ---------- convert small fp32 params (compact: only tensors actually copied) ----
#define NCVT 17
struct CvtArgs {
    const void* src[NCVT];
    unsigned dst[NCVT];       // dst offset (floats) in arena
    unsigned cum[NCVT + 1];   // cumulative element counts
    const int* cnt;
    float* dstA;
};
__global__ __launch_bounds__(256) void cvt_all(CvtArgs a) {
    unsigned i = blockIdx.x * 256 + threadIdx.x;
    if (i >= a.cum[NCVT]) return;
    bool isb = (*a.cnt == 0);
    int w = 0;
    while (i >= a.cum[w + 1]) w++;
    unsigned j = i - a.cum[w];
    float v = isb ? __bfloat162float(((const bf16*)a.src[w])[j])
                  : ((const float*)a.src[w])[j];
    a.dstA[a.dst[w] + j] = v;
}

// ---------- dtype-adaptive downcast straight from d_in ----------
__global__ __launch_bounds__(256) void f2bf_dyn(const void* __restrict__ src,
                                                bf16* __restrict__ d, int n,
                                                const int* __restrict__ cnt) {
    int i = blockIdx.x * 256 + threadIdx.x;
    if (i >= n) return;
    if (*cnt == 0) d[i] = ((const bf16*)src)[i];
    else           d[i] = __float2bfloat16(((const float*)src)[i]);
}

// ---------- conv2 weight permute: [c][ci][di][dj] -> [c][(di*5+dj)*32+ci] bf16 ----
__global__ __launch_bounds__(256) void w2perm(const void* __restrict__ src,
                                              bf16* __restrict__ d,
                                              const int* __restrict__ cnt) {
    int idx = blockIdx.x * 256 + threadIdx.x;
    if (idx >= 51200) return;
    int c = idx / 800, k = idx - c * 800;
    int kc = k >> 5, ci = k & 31;
    int di = kc / 5, dj = kc - di * 5;
    int s = ((c * 32 + ci) * 5 + di) * 5 + dj;
    float v = (*cnt == 0) ? __bfloat162float(((const bf16*)src)[s])
                          : ((const float*)src)[s];
    d[idx] = __float2bfloat16(v);
}

// ---------- conv1 + gelu + maxpool(14), LDS-tiled, channel-last bf16 out ----------
__global__ __launch_bounds__(256) void conv1_pool2(const float* __restrict__ spec,
                                                   const float* __restrict__ w1,
                                                   const float* __restrict__ b1,
                                                   bf16* __restrict__ P1c) {
    __shared__ float ss[18][256];
    __shared__ float sw[200];
    int jt = blockIdx.x, p = blockIdx.y, z = blockIdx.z;
    int b = z >> 2, cg = z & 3;
    int tid = threadIdx.x;
    for (int i = tid; i < 200; i += 256) sw[i] = w1[cg * 200 + i];
    int ibase = p * 14, c0 = jt * 250 - 2;
    for (int idx = tid; idx < 18 * 256; idx += 256) {
        int rr = idx >> 8, cc = idx & 255;
        int gi = ibase - 2 + rr, gj = c0 + cc;
        ss[rr][cc] = (gi >= 0 && gi < FBINS && gj >= 0 && gj < TT && cc < 254)
                         ? spec[(size_t)b * FBINS * TT + (size_t)gi * TT + gj] : 0.f;
    }
    __syncthreads();
    if (tid >= 250) return;
    int j = jt * 250 + tid;
    unsigned short* orow = (unsigned short*)P1c + ((size_t)((b * 14 + p) * 1000 + j)) * 32;
    for (int cpl = 0; cpl < 8; cpl += 2) {
        int cp = cg * 8 + cpl;
        float conv[2][14];
        float b0 = b1[cp], b1v = b1[cp + 1];
#pragma unroll
        for (int i = 0; i < 14; i++) { conv[0][i] = b0; conv[1][i] = b1v; }
        const float* w0 = sw + cpl * 25;
        const float* w1p = sw + (cpl + 1) * 25;
        for (int rr = 0; rr < 18; rr++) {
            float v0 = ss[rr][tid], v1 = ss[rr][tid + 1], v2 = ss[rr][tid + 2],
                  v3 = ss[rr][tid + 3], v4 = ss[rr][tid + 4];
#pragma unroll
            for (int di = 0; di < 5; di++) {
                int i = rr - di;
                if (i >= 0 && i < 14) {
                    conv[0][i] += v0 * w0[di * 5] + v1 * w0[di * 5 + 1] + v2 * w0[di * 5 + 2]
                                + v3 * w0[di * 5 + 3] + v4 * w0[di * 5 + 4];
                    conv[1][i] += v0 * w1p[di * 5] + v1 * w1p[di * 5 + 1] + v2 * w1p[di * 5 + 2]
                                + v3 * w1p[di * 5 + 3] + v4 * w1p[di * 5 + 4];
                }
            }
        }
        float mx0 = -1e30f, mn0 = 1e30f, mx1 = -1e30f, mn1 = 1e30f;
#pragma unroll
        for (int i = 0; i < 14; i++) {
            mx0 = fmaxf(mx0, conv[0][i]); mn0 = fminf(mn0, conv[0][i]);
            mx1 = fmaxf(mx1, conv[1][i]); mn1 = fminf(mn1, conv[1][i]);
        }
        float m0 = fmaxf(gelu_f(mx0), gelu_f(mn0));
        float m1 = fmaxf(gelu_f(mx1), gelu_f(mn1));
        bf16 mb0 = __float2bfloat16(m0), mb1 = __float2bfloat16(m1);
        unsigned pk = ((unsigned)(*(unsigned short*)&mb1) << 16) |
                      (unsigned)(*(unsigned short*)&mb0);
        *(unsigned*)(orow + cp) = pk;
    }
}

// ---------- conv2 implicit-GEMM ----------
__global__ __launch_bounds__(256) void conv2_gemm(const bf16* __restrict__ P1c,
                                                  const bf16* __restrict__ W2p,
                                                  const float* __restrict__ c2b,
                                                  bf16* __restrict__ convout) {
    __shared__ __align__(16) short Asm[64 * 40];
    __shared__ __align__(16) short Bsm[64 * 40];
    int tid = threadIdx.x, wave = tid >> 6, lane = tid & 63;
    int q = lane >> 4, l15 = lane & 15;
    int jt = blockIdx.x, i = blockIdx.y, b = blockIdx.z;
    int lrow = tid >> 2, lci = (tid & 3) * 8;
    int jrow = jt * 64 + lrow;
    int mw = (wave & 1) * 32, nw = (wave >> 1) * 32;
    floatx4 acc[2][2] = {};
    for (int di = 0; di < 5; di++) {
        int ii = i + di - 2;
        bool iok = (ii >= 0 && ii < 14);
        for (int dj = 0; dj < 5; dj++) {
            int kc = di * 5 + dj;
            {
                int jj = jrow + dj - 2;
                uint4 v = make_uint4(0u, 0u, 0u, 0u);
                if (iok && jrow < TT && jj >= 0 && jj < TT)
                    v = *(const uint4*)(P1c +
                        (((size_t)(b * 14 + ii)) * TT + jj) * 32 + lci);
                *(uint4*)(Asm + lrow * 40 + lci) = v;
            }
            {
                *(uint4*)(Bsm + lrow * 40 + lci) =
                    *(const uint4*)(W2p + (size_t)lrow * 800 + kc * 32 + lci);
            }
            __syncthreads();
            short8 a0 = *(const short8*)(Asm + (mw + l15) * 40 + q * 8);
            short8 a1 = *(const short8*)(Asm + (mw + 16 + l15) * 40 + q * 8);
            short8 b0 = *(const short8*)(Bsm + (nw + l15) * 40 + q * 8);
            short8 b1 = *(const short8*)(Bsm + (nw + 16 + l15) * 40 + q * 8);
            acc[0][0] = __builtin_amdgcn_mfma_f32_16x16x32_bf16(a0, b0, acc[0][0], 0, 0, 0);
            acc[0][1] = __builtin_amdgcn_mfma_f32_16x16x32_bf16(a0, b1, acc[0][1], 0, 0, 0);
            acc[1][0] = __builtin_amdgcn_mfma_f32_16x16x32_bf16(a1, b0, acc[1][0], 0, 0, 0);
            acc[1][1] = __builtin_amdgcn_mfma_f32_16x16x32_bf16(a1, b1, acc[1][1], 0, 0, 0);
            __syncthreads();
        }
    }
#pragma unroll
    for (int im = 0; im < 2; im++) {
#pragma unroll
        for (int jn = 0; jn < 2; jn++) {
            int c = nw + jn * 16 + l15;
            float bv = c2b[c];
#pragma unroll
            for (int r = 0; r < 4; r++) {
                int j = jt * 64 + mw + im * 16 + q * 4 + r;
                if (j >= TT) continue;
                convout[((size_t)(b * 14 + i) * TT + j) * 64 + c] =
                    __float2bfloat16(acc[im][jn][r] + bv);
            }
        }
    }
}

// ---------- conv2 epilogue: gelu + maxpool(14) + transpose (valley-trick) ----------
__global__ __launch_bounds__(256) void pool2_k(const bf16* __restrict__ convout,
                                               bf16* __restrict__ p2t) {
    int idx = blockIdx.x * 256 + threadIdx.x;
    if (idx >= 256000) return;
    int c = idx & 63, bj = idx >> 6;
    int b = bj / 1000, j = bj - b * 1000;
    float mx = -1e30f, mn = 1e30f;
#pragma unroll
    for (int i = 0; i < 14; i++) {
        float v = __bfloat162float(convout[((size_t)(b * 14 + i) * 1000 + j) * 64 + c]);
        mx = fmaxf(mx, v); mn = fminf(mn, v);
    }
    p2t[(size_t)bj * 64 + c] = __float2bfloat16(fmaxf(gelu_f(mx), gelu_f(mn)));
}

// ---------- layernorm: fp32 in -> bf16 out ----------
__global__ __launch_bounds__(256) void layernorm_k(const float* __restrict__ x,
                                                   const float* __restrict__ g,
                                                   const float* __restrict__ bta,
                                                   bf16* __restrict__ y) {
    __shared__ float red[256];
    int row = blockIdx.x, tid = threadIdx.x;
    const float* xr = x + (size_t)row * DM;
    float v0 = xr[tid], v1 = xr[tid + 256];
    red[tid] = v0 + v1;
    __syncthreads();
    for (int s = 128; s > 0; s >>= 1) { if (tid < s) red[tid] += red[tid + s]; __syncthreads(); }
    float mu = red[0] * (1.f / 512.f);
    __syncthreads();
    float d0 = v0 - mu, d1 = v1 - mu;
    red[tid] = d0 * d0 + d1 * d1;
    __syncthreads();
    for (int s = 128; s > 0; s >>= 1) { if (tid < s) red[tid] += red[tid + s]; __syncthreads(); }
    float rstd = rsqrtf(red[0] * (1.f / 512.f) + 1e-5f);
    bf16* yr = y + (size_t)row * DM;
    yr[tid]       = __float2bfloat16(d0 * rstd * g[tid]       + bta[tid]);
    yr[tid + 256] = __float2bfloat16(d1 * rstd * g[tid + 256] + bta[tid + 256]);
}

// ---------- deproj GEMM (fp32) writing d_out dtype-adaptively ----------
__global__ __launch_bounds__(256) void gemm_out(const float* __restrict__ A,
                                                const float* __restrict__ B,
                                                const float* __restrict__ bias,
                                                const int* __restrict__ cnt,
                                                void* __restrict__ dout,
                                                int M, int N, int K) {
    __shared__ float As[32][33];
    __shared__ float Bs[32][33];
    int tid = threadIdx.x;
    int tx = tid & 15, ty = tid >> 4;
    int m0 = blockIdx.x * 32, n0 = blockIdx.y * 32;
    float c[2][2] = {};
    for (int k0 = 0; k0 < K; k0 += 32) {
#pragma unroll
        for (int i = 0; i < 4; i++) {
            int idx = i * 256 + tid;
            int r = idx >> 5, kk = idx & 31;
            int gm = m0 + r;
            As[r][kk] = (gm < M) ? A[(size_t)gm * K + k0 + kk] : 0.f;
            Bs[r][kk] = B[(size_t)(n0 + r) * K + k0 + kk];
        }
        __syncthreads();
#pragma unroll
        for (int k = 0; k < 32; k++) {
            float a0 = As[ty * 2][k], a1 = As[ty * 2 + 1][k];
            float b0 = Bs[tx * 2][k], b1 = Bs[tx * 2 + 1][k];
            c[0][0] += a0 * b0; c[0][1] += a0 * b1;
            c[1][0] += a1 * b0; c[1][1] += a1 * b1;
        }
        __syncthreads();
    }
    bool isb = (*cnt == 0);
#pragma unroll
    for (int i = 0; i < 2; i++) {
        int m = m0 + ty * 2 + i;
        if (m >= M) continue;
#pragma unroll
        for (int jj = 0; jj < 2; jj++) {
            int n = n0 + tx * 2 + jj;
            float v = c[i][jj] + bias[n];
            if (isb) ((bf16*)dout)[(size_t)m * N + n] = __float2bfloat16(v);
            else     ((float*)dout)[(size_t)m * N + n] = v;
        }
    }
}

// ---------- unified MFMA bf16 NT GEMM, BM(M) x NT(N) tile ----------
template <int BM, int NT, int ROUTE, int ACT, bool OUT_BF16>
__global__ __launch_bounds__(256) void mfma_big(const bf16* __restrict__ A,
                                                const bf16* __restrict__ B,
                                                const float* __restrict__ bias,
                                                const float* __restrict__ resid,
                                                float* __restrict__ Cf,
                                                bf16* __restrict__ Cb,
                                                int M, int N, int K,
                                                size_t wstride, int bstride,
                                                size_t ostride) {
    __shared__ __align__(16) short Asm[BM * 40];
    __shared__ __align__(16) short Bsm[NT * 40];
    int tid = threadIdx.x, wave = tid >> 6, lane = tid & 63;
    int q = lane >> 4, l15 = lane & 15;
    int m0 = blockIdx.x * BM, n0 = blockIdx.y * NT;
    int lrow = tid >> 2, lk = (tid & 3) * 8;
    constexpr int MF = (NT == 128) ? (BM / 16) : (BM / 32);
    int m0w = (NT == 128) ? 0 : ((wave >> 1) * (BM / 2));
    int nfb = (NT == 128) ? (wave * 32) : ((wave & 1) * 32);
    floatx4 acc[MF][2] = {};
    for (int k0 = 0; k0 < K; k0 += 32) {
#pragma unroll
        for (int hh = 0; hh < BM / 64; hh++) {
            int row = lrow + hh * 64, gm = m0 + row;
            uint4 v = make_uint4(0u, 0u, 0u, 0u);
            if (gm < M) v = *(const uint4*)(A + (size_t)gm * K + k0 + lk);
            *(uint4*)(Asm + row * 40 + lk) = v;
        }
#pragma unroll
        for (int hh = 0; hh < NT / 64; hh++) {
            int row = lrow + hh * 64, gn = n0 + row;
            const bf16* src = ROUTE
                ? B + (size_t)(gn >> 9) * wstride + (size_t)(gn & 511) * K + k0 + lk
                : B + (size_t)gn * K + k0 + lk;
            *(uint4*)(Bsm + row * 40 + lk) = *(const uint4*)src;
        }
        __syncthreads();
        short8 a[MF], b2[2];
#pragma unroll
        for (int im = 0; im < MF; im++)
            a[im] = *(const short8*)(Asm + (m0w + im * 16 + l15) * 40 + q * 8);
#pragma unroll
        for (int jn = 0; jn < 2; jn++)
            b2[jn] = *(const short8*)(Bsm + (nfb + jn * 16 + l15) * 40 + q * 8);
#pragma unroll
        for (int im = 0; im < MF; im++)
#pragma unroll
            for (int jn = 0; jn < 2; jn++)
                acc[im][jn] = __builtin_amdgcn_mfma_f32_16x16x32_bf16(
                    a[im], b2[jn], acc[im][jn], 0, 0, 0);
        __syncthreads();
    }
#pragma unroll
    for (int im = 0; im < MF; im++) {
#pragma unroll
        for (int jn = 0; jn < 2; jn++) {
            int nn = n0 + nfb + jn * 16 + l15;
            float bval = ROUTE ? bias[(nn >> 9) * bstride + (nn & 511)] : bias[nn];
#pragma unroll
            for (int r = 0; r < 4; r++) {
                int m = m0 + m0w + im * 16 + q * 4 + r;
                if (m >= M) continue;
                float v = acc[im][jn][r] + bval;
                if (resid) v += resid[(size_t)m * N + nn];
                if (ACT == 1) v = fmaxf(v, 0.f);
                if (ROUTE)
                    Cb[(size_t)(nn >> 9) * ostride + (size_t)m * 512 + (nn & 511)] =
                        __float2bfloat16(v);
                else if (OUT_BF16)
                    Cb[(size_t)m * N + nn] = __float2bfloat16(v);
                else
                    Cf[(size_t)m * N + nn] = v;
            }
        }
    }
}

// ---------- V transpose: Vb[b,t,h*64+d] -> Vt[z][d][t] (stride 1024, zero-pad) ----
__global__ __launch_bounds__(256) void vt_k(const bf16* __restrict__ Vb,
                                            bf16* __restrict__ Vt) {
    __shared__ short tile[64][65];
    int t0 = blockIdx.x * 64, z = blockIdx.y;
    int b = z >> 3, h = z & 7;
    int tid = threadIdx.x;
#pragma unroll
    for (int i = 0; i < 16; i++) {
        int tr = i * 4 + (tid >> 6), d = tid & 63;
        int t = t0 + tr;
        bf16 v = (t < TT) ? Vb[((size_t)b * TT + t) * DM + h * 64 + d] : (bf16)__float2bfloat16(0.f);
        tile[tr][d] = *(short*)&v;
    }
    __syncthreads();
#pragma unroll
    for (int i = 0; i < 16; i++) {
        int dr = i * 4 + (tid >> 6), tc = tid & 63;
        *(short*)&Vt[(size_t)z * 65536 + dr * 1024 + t0 + tc] = tile[tc][dr];
    }
}

// ---------- fused attention, KVBLK=64 LDS diet: 49.9 KB -> 3 blocks/CU ----------
// R14 attn was latency/barrier-bound at 2 blocks/CU (LDS 74.7 KB cap; MFMA 8.8%,
// VALU 29%, HBM 7.6% — nothing saturated). KVBLK 128->64 shrinks every t-sized
// buffer: Qs 12.8K + pool 17.7K (K 64x40 + E 128x40; G overlay 65x136) +
// Pl/Vs 9.2K each + rsw 1K = 49.9 KB -> 3 blocks/CU with launch_bounds(256,3)
// (VGPR cap 170; live set ~140, no spill). Cost: +16% MFMA (worse G-window
// overlap) and 2x barriers — hidden by 1.5x co-resident blocks.
// Gather algebra (R5-verified skeleton, n-dim halved): dd = nl + 64 - ur.
__global__ __launch_bounds__(256, 3) void attn_fused(const bf16* __restrict__ Q,
                                                     const bf16* __restrict__ K,
                                                     const bf16* __restrict__ Er,
                                                     const bf16* __restrict__ Vt,
                                                     bf16* __restrict__ AO) {
    __shared__ __align__(16) short Qs[6400];      // [2 kh][80][40]
    __shared__ __align__(16) short pool[8840];    // K 64x40 @0 + E 128x40 @2560; G 65x136 overlay
    __shared__ __align__(16) short Pl[64 * 72];   // P chunk (bf16), rows m
    __shared__ __align__(16) short Vs[64 * 72];   // V chunk (d-major)
    __shared__ float rsw[4][64];
    int tid = threadIdx.x, wave = tid >> 6, lane = tid & 63;
    int q = lane >> 4, l15 = lane & 15;
    int m0 = blockIdx.x * 64;
    int z = blockIdx.z, b = z >> 3, h = z & 7;
    const bf16* Ap = Q + (size_t)b * TT * DM + h * 64;
    const bf16* Bp = K + (size_t)b * TT * DM + h * 64;
    const bf16* Vp = Vt + (size_t)z * 65536;
    int lrow = tid >> 2, lk = (tid & 3) * 8;
    int mw = wave * 16;

    // stage Q rows m0..m0+79, both 32-depth halves (persistent)
#pragma unroll
    for (int kh = 0; kh < 2; kh++) {
        int gm = m0 + lrow;
        uint4 v = make_uint4(0u, 0u, 0u, 0u);
        if (gm < TT) v = *(const uint4*)(Ap + (size_t)gm * DM + kh * 32 + lk);
        *(uint4*)(Qs + kh * 3200 + lrow * 40 + lk) = v;
        if (tid < 64) {
            int rr = 64 + (tid >> 2);
            int g2 = m0 + rr;
            uint4 v2 = make_uint4(0u, 0u, 0u, 0u);
            if (g2 < TT) v2 = *(const uint4*)(Ap + (size_t)g2 * DM + kh * 32 + lk);
            *(uint4*)(Qs + kh * 3200 + rr * 40 + lk) = v2;
        }
    }

    float rsum[16];
#pragma unroll
    for (int i = 0; i < 16; i++) rsum[i] = 0.f;
    floatx4 accO[4] = {};

    for (int tc = 0; tc < 16; tc++) {
        int t0 = tc * 64;
        int db = t0 - m0 - 64;
        floatx4 accS[4] = {};
        floatx4 accG[5][2] = {};
        for (int k0 = 0; k0 < 64; k0 += 32) {
            {   // K: 64 rows x 32
                int gn = t0 + lrow;
                uint4 v = make_uint4(0u, 0u, 0u, 0u);
                if (gn < TT) v = *(const uint4*)(Bp + (size_t)gn * DM + k0 + lk);
                *(uint4*)(pool + lrow * 40 + lk) = v;
            }
            {   // E: 128 rows x 32 (shift-gathered Er'')
#pragma unroll
                for (int hh = 0; hh < 2; hh++) {
                    int dd = lrow + hh * 64;
                    int dl = db + dd;
                    int src = (dl <= 0) ? (999 + dl) : (dl - 1);
                    uint4 v = make_uint4(0u, 0u, 0u, 0u);
                    if (src >= 0 && src < TT)
                        v = *(const uint4*)(Er + (size_t)src * 64 + k0 + lk);
                    *(uint4*)(pool + 2560 + dd * 40 + lk) = v;
                }
            }
            if (k0 == 0) {  // V chunk: 64 d-rows x 64 t-cols, 8 shorts/store
#pragma unroll
                for (int e2 = 0; e2 < 2; e2++) {
                    int li = tid + e2 * 256;
                    int row = li >> 3, cs = (li & 7) * 8;
                    *(uint4*)(Vs + row * 72 + cs) =
                        *(const uint4*)(Vp + (size_t)row * 1024 + t0 + cs);
                }
            }
            __syncthreads();
            short8 a[5], bk, e[2];
#pragma unroll
            for (int im = 0; im < 5; im++)
                a[im] = *(const short8*)(Qs + (k0 >> 5) * 3200 + (im * 16 + l15) * 40 + q * 8);
            bk = *(const short8*)(pool + (wave * 16 + l15) * 40 + q * 8);
#pragma unroll
            for (int jg = 0; jg < 2; jg++)
                e[jg] = *(const short8*)(pool + 2560 + (wave * 32 + jg * 16 + l15) * 40 + q * 8);
            __builtin_amdgcn_s_setprio(1);
#pragma unroll
            for (int im = 0; im < 4; im++)
                accS[im] = __builtin_amdgcn_mfma_f32_16x16x32_bf16(
                    a[im], bk, accS[im], 0, 0, 0);
#pragma unroll
            for (int im = 0; im < 5; im++)
#pragma unroll
                for (int jg = 0; jg < 2; jg++)
                    accG[im][jg] = __builtin_amdgcn_mfma_f32_16x16x32_bf16(
                        a[im], e[jg], accG[im][jg], 0, 0, 0);
            __builtin_amdgcn_s_setprio(0);
            __syncthreads();
        }
        // write G rows 0..64 to LDS (overlay pool [65][136]) as bf16
#pragma unroll
        for (int im = 0; im < 5; im++)
#pragma unroll
            for (int jg = 0; jg < 2; jg++) {
                int col = wave * 32 + jg * 16 + l15;
#pragma unroll
                for (int r = 0; r < 4; r++) {
                    int row = im * 16 + q * 4 + r;
                    if (row < 65) {
                        bf16 gv = __float2bfloat16(accG[im][jg][r]);
                        pool[row * 136 + col] = *(short*)&gv;
                    }
                }
            }
        __syncthreads();
        // epilogue: rel gather + exp + rowsum + P write (16 n-cols per wave)
#pragma unroll
        for (int im = 0; im < 4; im++) {
            int nl = wave * 16 + l15;
            int n = t0 + nl;
#pragma unroll
            for (int r = 0; r < 4; r++) {
                int ml = im * 16 + q * 4 + r;
                int m = m0 + ml;
                float pe = 0.f;
                if (n < TT) {
                    float rel = 0.f;
                    if (n != m + 1) {
                        int ur = (n <= m) ? ml : (ml + 1);
                        int dd = nl + 64 - ur;
                        short gs = pool[ur * 136 + dd];
                        rel = __bfloat162float(*(bf16*)&gs);
                    }
                    pe = __expf((accS[im][r] + rel) * 0.125f - PSHIFT);
                    rsum[im * 4 + r] += pe;
                }
                bf16 pb = __float2bfloat16(pe);
                Pl[ml * 72 + nl] = *(short*)&pb;
            }
        }
        __syncthreads();
        // PV: each wave owns m-rows mw..mw+15, all 64 d-cols
        __builtin_amdgcn_s_setprio(1);
#pragma unroll
        for (int kc = 0; kc < 2; kc++) {
            short8 a = *(const short8*)(Pl + (mw + l15) * 72 + kc * 32 + q * 8);
#pragma unroll
            for (int jn = 0; jn < 4; jn++) {
                short8 bv = *(const short8*)(Vs + (jn * 16 + l15) * 72 + kc * 32 + q * 8);
                accO[jn] = __builtin_amdgcn_mfma_f32_16x16x32_bf16(a, bv, accO[jn], 0, 0, 0);
            }
        }
        __builtin_amdgcn_s_setprio(0);
        __syncthreads();
    }
    // rowsum: butterfly over the 16 l15 lanes, then sum 4 waves via LDS
#pragma unroll
    for (int t = 0; t < 16; t++) {
        float s = rsum[t];
        s += __shfl_xor(s, 1, 64); s += __shfl_xor(s, 2, 64);
        s += __shfl_xor(s, 4, 64); s += __shfl_xor(s, 8, 64);
        if (l15 == 0) rsw[wave][(t >> 2) * 16 + q * 4 + (t & 3)] = s;
    }
    __syncthreads();
#pragma unroll
    for (int r = 0; r < 4; r++) {
        int lm = mw + q * 4 + r;
        int m = m0 + lm;
        if (m >= TT) continue;
        float tot = rsw[0][lm] + rsw[1][lm] + rsw[2][lm] + rsw[3][lm];
        float inv = 1.f / tot;
#pragma unroll
        for (int jn = 0; jn < 4; jn++)
            AO[((size_t)b * TT + m) * DM + h * 64 + jn * 16 + l15] =
                __float2bfloat16(accO[jn][r] * inv);
    }
}

// ---------- launch ----------
extern "C" void kernel_launch(void* const* d_in, const int* in_sizes, int n_in,
                              void* d_out, int out_size, void* d_ws, size_t ws_size,
                              hipStream_t stream) {
    if (!g_arena) (void)hipMalloc(&g_arena, ARENA_BYTES);
    float* A = (float*)g_arena;

    static const unsigned off[27] = {
        0, 784000, 784800, 784832, 836032, 836096, 868864, 869376, 871424,
        873472, 1922048, 2970624, 4019200, 5067776, 5069824, 5071872,
        5073920, 5075968, 5331968, 5334016, 5336064, 9530368, 9538560,
        13732864, 13734912, 13800448, 13800576};
    const float* spec  = A + off[0];
    const float* c1w   = A + off[1];
    const float* c1b   = A + off[2];
    const float* c2b   = A + off[4];
    const float* projb = A + off[6];
    const float* ln1g  = A + off[7];
    const float* ln1b  = A + off[8];
    const float* qb    = A + off[13];
    const float* db    = A + off[16];
    const float* ln2g  = A + off[18];
    const float* ln2b  = A + off[19];
    const float* f1b   = A + off[21];
    const float* f2b_  = A + off[23];
    const float* depw  = A + off[24];
    const float* depb  = A + off[25];

    const size_t PA = 13800576;
    float* x    = A + PA;
    float* P1   = x + 2048000;               // hosts P1c (bf16)
    float* SM   = P1 + 1792000;
    bf16* P1c     = (bf16*)P1;               // [4,14,1000,32] bf16
    bf16* p2t_b   = (bf16*)SM;
    bf16* projw_b = (bf16*)(SM + 128000);
    bf16* w2p     = (bf16*)(SM + 150000);    // [64][800] permuted conv2 weights
    int*   cnt  = (int*)(SM + 256000);
    float* ScF  = SM + 256004;               // scratch region
    float* B0   = ScF + 32000000;
    bf16* wb_qkvd = (bf16*)B0;
    bf16* wb_f1   = (bf16*)(B0 + 2097152);
    bf16* wb_f2   = (bf16*)(B0 + 4194304);
    bf16* Erb     = (bf16*)(B0 + 6291456);
    bf16* xn_b    = (bf16*)(B0 + 6419456);
    bf16* AO_b    = (bf16*)(B0 + 7443456);
    bf16* Qb_b    = (bf16*)(B0 + 8467456);
    bf16* Kb_b    = (bf16*)(B0 + 9491456);
    bf16* Vb_b    = (bf16*)(B0 + 10515456);
    bf16* FFH_b   = (bf16*)(B0 + 11539456);
    bf16* Vt      = (bf16*)(B0 + 15635456);
    bf16* convout = (bf16*)(B0 + 16684032);  // pre-loop scratch [56000,64]

    hipMemsetAsync(cnt, 0, sizeof(int), stream);
    sniff_k<<<1024, 256, 0, stream>>>((const unsigned short*)d_in[20], 1000000, cnt);

    // compact fp32-copy table: only the tensors that actually get copied.
    static const int cvt_ids[NCVT] = {0, 1, 2, 4, 6, 7, 8, 13, 14, 15, 16,
                                      18, 19, 21, 23, 24, 25};
    CvtArgs ca;
    unsigned cum = 0;
    for (int t = 0; t < NCVT; t++) {
        int w = cvt_ids[t];
        ca.src[t] = d_in[w];
        ca.dst[t] = off[w];
        ca.cum[t] = cum;
        cum += off[w + 1] - off[w];
    }
    ca.cum[NCVT] = cum;   // 877,696
    ca.cnt = cnt; ca.dstA = A;
    cvt_all<<<(cum + 255) / 256, 256, 0, stream>>>(ca);

    // big weights: straight dtype-adaptive downcast from d_in
    for (int t = 0; t < 4; t++)
        f2bf_dyn<<<4096, 256, 0, stream>>>(d_in[9 + t], wb_qkvd + (size_t)t * 1048576,
                                           1048576, cnt);
    f2bf_dyn<<<16384, 256, 0, stream>>>(d_in[20], wb_f1, 4194304, cnt);
    f2bf_dyn<<<16384, 256, 0, stream>>>(d_in[22], wb_f2, 4194304, cnt);
    f2bf_dyn<<<1000,  256, 0, stream>>>(d_in[17], Erb,   256000, cnt);
    f2bf_dyn<<<128,   256, 0, stream>>>(d_in[5],  projw_b, 32768, cnt);
    w2perm<<<200, 256, 0, stream>>>(d_in[3], w2p, cnt);

    // conv frontend (implicit-GEMM conv2; no im2col)
    conv1_pool2<<<dim3(4, 14, 16), 256, 0, stream>>>(spec, c1w, c1b, P1c);
    conv2_gemm<<<dim3(16, 14, 4), 256, 0, stream>>>(P1c, w2p, c2b, convout);
    pool2_k<<<1000, 256, 0, stream>>>(convout, p2t_b);
    mfma_big<64, 64, 0, 0, false><<<dim3(63, 8), 256, 0, stream>>>(
        p2t_b, projw_b, projb, nullptr, x, nullptr, BT, DM, 64, 0, 0, 0);

    for (int l = 0; l < LL; l++) {
        layernorm_k<<<BT, 256, 0, stream>>>(x, ln1g + l * DM, ln1b + l * DM, xn_b);
        mfma_big<64, 128, 1, 0, true><<<dim3(63, 12), 256, 0, stream>>>(
            xn_b, wb_qkvd + (size_t)l * DM * DM, qb + l * DM, nullptr,
            nullptr, Qb_b, BT, 1536, DM, 1048576, 2048, 2048000);
        vt_k<<<dim3(16, 32), 256, 0, stream>>>(Vb_b, Vt);
        attn_fused<<<dim3(16, 1, 32), 256, 0, stream>>>(
            Qb_b, Kb_b, Erb + (size_t)l * TT * DEPTH, Vt, AO_b);
        mfma_big<64, 64, 0, 0, false><<<dim3(63, 8), 256, 0, stream>>>(
            AO_b, wb_qkvd + 3 * 1048576 + (size_t)l * DM * DM, db + l * DM, x,
            x, nullptr, BT, DM, DM, 0, 0, 0);
        layernorm_k<<<BT, 256, 0, stream>>>(x, ln2g + l * DM, ln2b + l * DM, xn_b);
        mfma_big<64, 128, 0, 1, true><<<dim3(63, 16), 256, 0, stream>>>(
            xn_b, wb_f1 + (size_t)l * FFN * DM, f1b + l * FFN, nullptr,
            nullptr, FFH_b, BT, FFN, DM, 0, 0, 0);
        mfma_big<64, 64, 0, 0, false><<<dim3(63, 8), 256, 0, stream>>>(
            FFH_b, wb_f2 + (size_t)l * DM * FFN, f2b_ + l * DM, x,
            x, nullptr, BT, DM, FFN, 0, 0, 0);
    }

    gemm_out<<<dim3(125, 4), 256, 0, stream>>>(x, depw, depb, cnt, d_out, BT, EDIM, DM);
}

// Round 16
// 1087.035 us; speedup vs baseline: 1.0508x; 1.0508x over previous
//
#include <hip/hip_runtime.h>
#include <hip/hip_bf16.h>
#include <hip/hip_fp16.h>
#include <math.h>

// ---------- constants ----------
#define BB 4
#define FBINS 196
#define TT 1000
#define DM 512
#define HH 8
#define DEPTH 64
#define FFN 2048
#define LL 4
#define EDIM 128
#define BT (BB*TT)   // 4000
#define PSHIFT 12.0f

typedef __hip_bfloat16 bf16;
typedef __attribute__((ext_vector_type(8))) short short8;
typedef __attribute__((ext_vector_type(4))) float floatx4;

// ---------- private arena ----------
#define ARENA_BYTES 420000000ULL
static void* g_arena = nullptr;
__attribute__((constructor)) static void arena_init() {
    if (!g_arena) (void)hipMalloc(&g_arena, ARENA_BYTES);
}

__device__ __forceinline__ float gelu_f(float x) {
    return 0.5f * x * (1.0f + erff(x * 0.70710678118654752440f));
}
// gelu is valley-shaped (decreasing then increasing, min at x~-0.7518), so
// max_i gelu(x_i) == max(gelu(min_i x_i), gelu(max_i x_i)) EXACTLY.

// ---------- dtype sniffer (cnt==0 <=> inputs are bf16) ----------
__global__ __launch_bounds__(256) void sniff_k(const unsigned short* __restrict__ p,
                                               int n, int* __restrict__ cnt) {
    int i = blockIdx.x * 256 + threadIdx.x;
    int c = 0;
    for (; i < n; i += gridDim.x * 256) {
        unsigned short u = p[i];
        if ((unsigned short)(u & 0x7FFF) > (unsigned short)0x7F80) c++;
    }
    if (c) atomicAdd(cnt, c);
}

// ---------- convert small fp32 params (compact: only tensors actually copied) ----
#define NCVT 17
struct CvtArgs {
    const void* src[NCVT];
    unsigned dst[NCVT];       // dst offset (floats) in arena
    unsigned cum[NCVT + 1];   // cumulative element counts
    const int* cnt;
    float* dstA;
};
__global__ __launch_bounds__(256) void cvt_all(CvtArgs a) {
    unsigned i = blockIdx.x * 256 + threadIdx.x;
    if (i >= a.cum[NCVT]) return;
    bool isb = (*a.cnt == 0);
    int w = 0;
    while (i >= a.cum[w + 1]) w++;
    unsigned j = i - a.cum[w];
    float v = isb ? __bfloat162float(((const bf16*)a.src[w])[j])
                  : ((const float*)a.src[w])[j];
    a.dstA[a.dst[w] + j] = v;
}

// ---------- dtype-adaptive downcast straight from d_in ----------
__global__ __launch_bounds__(256) void f2bf_dyn(const void* __restrict__ src,
                                                bf16* __restrict__ d, int n,
                                                const int* __restrict__ cnt) {
    int i = blockIdx.x * 256 + threadIdx.x;
    if (i >= n) return;
    if (*cnt == 0) d[i] = ((const bf16*)src)[i];
    else           d[i] = __float2bfloat16(((const float*)src)[i]);
}

// ---------- conv2 weight permute: [c][ci][di][dj] -> [c][(di*5+dj)*32+ci] bf16 ----
__global__ __launch_bounds__(256) void w2perm(const void* __restrict__ src,
                                              bf16* __restrict__ d,
                                              const int* __restrict__ cnt) {
    int idx = blockIdx.x * 256 + threadIdx.x;
    if (idx >= 51200) return;
    int c = idx / 800, k = idx - c * 800;
    int kc = k >> 5, ci = k & 31;
    int di = kc / 5, dj = kc - di * 5;
    int s = ((c * 32 + ci) * 5 + di) * 5 + dj;
    float v = (*cnt == 0) ? __bfloat162float(((const bf16*)src)[s])
                          : ((const float*)src)[s];
    d[idx] = __float2bfloat16(v);
}

// ---------- conv1 + gelu + maxpool(14), LDS-tiled, channel-last bf16 out ----------
__global__ __launch_bounds__(256) void conv1_pool2(const float* __restrict__ spec,
                                                   const float* __restrict__ w1,
                                                   const float* __restrict__ b1,
                                                   bf16* __restrict__ P1c) {
    __shared__ float ss[18][256];
    __shared__ float sw[200];
    int jt = blockIdx.x, p = blockIdx.y, z = blockIdx.z;
    int b = z >> 2, cg = z & 3;
    int tid = threadIdx.x;
    for (int i = tid; i < 200; i += 256) sw[i] = w1[cg * 200 + i];
    int ibase = p * 14, c0 = jt * 250 - 2;
    for (int idx = tid; idx < 18 * 256; idx += 256) {
        int rr = idx >> 8, cc = idx & 255;
        int gi = ibase - 2 + rr, gj = c0 + cc;
        ss[rr][cc] = (gi >= 0 && gi < FBINS && gj >= 0 && gj < TT && cc < 254)
                         ? spec[(size_t)b * FBINS * TT + (size_t)gi * TT + gj] : 0.f;
    }
    __syncthreads();
    if (tid >= 250) return;
    int j = jt * 250 + tid;
    unsigned short* orow = (unsigned short*)P1c + ((size_t)((b * 14 + p) * 1000 + j)) * 32;
    for (int cpl = 0; cpl < 8; cpl += 2) {
        int cp = cg * 8 + cpl;
        float conv[2][14];
        float b0 = b1[cp], b1v = b1[cp + 1];
#pragma unroll
        for (int i = 0; i < 14; i++) { conv[0][i] = b0; conv[1][i] = b1v; }
        const float* w0 = sw + cpl * 25;
        const float* w1p = sw + (cpl + 1) * 25;
        for (int rr = 0; rr < 18; rr++) {
            float v0 = ss[rr][tid], v1 = ss[rr][tid + 1], v2 = ss[rr][tid + 2],
                  v3 = ss[rr][tid + 3], v4 = ss[rr][tid + 4];
#pragma unroll
            for (int di = 0; di < 5; di++) {
                int i = rr - di;
                if (i >= 0 && i < 14) {
                    conv[0][i] += v0 * w0[di * 5] + v1 * w0[di * 5 + 1] + v2 * w0[di * 5 + 2]
                                + v3 * w0[di * 5 + 3] + v4 * w0[di * 5 + 4];
                    conv[1][i] += v0 * w1p[di * 5] + v1 * w1p[di * 5 + 1] + v2 * w1p[di * 5 + 2]
                                + v3 * w1p[di * 5 + 3] + v4 * w1p[di * 5 + 4];
                }
            }
        }
        float mx0 = -1e30f, mn0 = 1e30f, mx1 = -1e30f, mn1 = 1e30f;
#pragma unroll
        for (int i = 0; i < 14; i++) {
            mx0 = fmaxf(mx0, conv[0][i]); mn0 = fminf(mn0, conv[0][i]);
            mx1 = fmaxf(mx1, conv[1][i]); mn1 = fminf(mn1, conv[1][i]);
        }
        float m0 = fmaxf(gelu_f(mx0), gelu_f(mn0));
        float m1 = fmaxf(gelu_f(mx1), gelu_f(mn1));
        bf16 mb0 = __float2bfloat16(m0), mb1 = __float2bfloat16(m1);
        unsigned pk = ((unsigned)(*(unsigned short*)&mb1) << 16) |
                      (unsigned)(*(unsigned short*)&mb0);
        *(unsigned*)(orow + cp) = pk;
    }
}

// ---------- conv2 implicit-GEMM ----------
__global__ __launch_bounds__(256) void conv2_gemm(const bf16* __restrict__ P1c,
                                                  const bf16* __restrict__ W2p,
                                                  const float* __restrict__ c2b,
                                                  bf16* __restrict__ convout) {
    __shared__ __align__(16) short Asm[64 * 40];
    __shared__ __align__(16) short Bsm[64 * 40];
    int tid = threadIdx.x, wave = tid >> 6, lane = tid & 63;
    int q = lane >> 4, l15 = lane & 15;
    int jt = blockIdx.x, i = blockIdx.y, b = blockIdx.z;
    int lrow = tid >> 2, lci = (tid & 3) * 8;
    int jrow = jt * 64 + lrow;
    int mw = (wave & 1) * 32, nw = (wave >> 1) * 32;
    floatx4 acc[2][2] = {};
    for (int di = 0; di < 5; di++) {
        int ii = i + di - 2;
        bool iok = (ii >= 0 && ii < 14);
        for (int dj = 0; dj < 5; dj++) {
            int kc = di * 5 + dj;
            {
                int jj = jrow + dj - 2;
                uint4 v = make_uint4(0u, 0u, 0u, 0u);
                if (iok && jrow < TT && jj >= 0 && jj < TT)
                    v = *(const uint4*)(P1c +
                        (((size_t)(b * 14 + ii)) * TT + jj) * 32 + lci);
                *(uint4*)(Asm + lrow * 40 + lci) = v;
            }
            {
                *(uint4*)(Bsm + lrow * 40 + lci) =
                    *(const uint4*)(W2p + (size_t)lrow * 800 + kc * 32 + lci);
            }
            __syncthreads();
            short8 a0 = *(const short8*)(Asm + (mw + l15) * 40 + q * 8);
            short8 a1 = *(const short8*)(Asm + (mw + 16 + l15) * 40 + q * 8);
            short8 b0 = *(const short8*)(Bsm + (nw + l15) * 40 + q * 8);
            short8 b1 = *(const short8*)(Bsm + (nw + 16 + l15) * 40 + q * 8);
            acc[0][0] = __builtin_amdgcn_mfma_f32_16x16x32_bf16(a0, b0, acc[0][0], 0, 0, 0);
            acc[0][1] = __builtin_amdgcn_mfma_f32_16x16x32_bf16(a0, b1, acc[0][1], 0, 0, 0);
            acc[1][0] = __builtin_amdgcn_mfma_f32_16x16x32_bf16(a1, b0, acc[1][0], 0, 0, 0);
            acc[1][1] = __builtin_amdgcn_mfma_f32_16x16x32_bf16(a1, b1, acc[1][1], 0, 0, 0);
            __syncthreads();
        }
    }
#pragma unroll
    for (int im = 0; im < 2; im++) {
#pragma unroll
        for (int jn = 0; jn < 2; jn++) {
            int c = nw + jn * 16 + l15;
            float bv = c2b[c];
#pragma unroll
            for (int r = 0; r < 4; r++) {
                int j = jt * 64 + mw + im * 16 + q * 4 + r;
                if (j >= TT) continue;
                convout[((size_t)(b * 14 + i) * TT + j) * 64 + c] =
                    __float2bfloat16(acc[im][jn][r] + bv);
            }
        }
    }
}

// ---------- conv2 epilogue: gelu + maxpool(14) + transpose (valley-trick) ----------
__global__ __launch_bounds__(256) void pool2_k(const bf16* __restrict__ convout,
                                               bf16* __restrict__ p2t) {
    int idx = blockIdx.x * 256 + threadIdx.x;
    if (idx >= 256000) return;
    int c = idx & 63, bj = idx >> 6;
    int b = bj / 1000, j = bj - b * 1000;
    float mx = -1e30f, mn = 1e30f;
#pragma unroll
    for (int i = 0; i < 14; i++) {
        float v = __bfloat162float(convout[((size_t)(b * 14 + i) * 1000 + j) * 64 + c]);
        mx = fmaxf(mx, v); mn = fminf(mn, v);
    }
    p2t[(size_t)bj * 64 + c] = __float2bfloat16(fmaxf(gelu_f(mx), gelu_f(mn)));
}

// ---------- layernorm: fp32 in -> bf16 out ----------
__global__ __launch_bounds__(256) void layernorm_k(const float* __restrict__ x,
                                                   const float* __restrict__ g,
                                                   const float* __restrict__ bta,
                                                   bf16* __restrict__ y) {
    __shared__ float red[256];
    int row = blockIdx.x, tid = threadIdx.x;
    const float* xr = x + (size_t)row * DM;
    float v0 = xr[tid], v1 = xr[tid + 256];
    red[tid] = v0 + v1;
    __syncthreads();
    for (int s = 128; s > 0; s >>= 1) { if (tid < s) red[tid] += red[tid + s]; __syncthreads(); }
    float mu = red[0] * (1.f / 512.f);
    __syncthreads();
    float d0 = v0 - mu, d1 = v1 - mu;
    red[tid] = d0 * d0 + d1 * d1;
    __syncthreads();
    for (int s = 128; s > 0; s >>= 1) { if (tid < s) red[tid] += red[tid + s]; __syncthreads(); }
    float rstd = rsqrtf(red[0] * (1.f / 512.f) + 1e-5f);
    bf16* yr = y + (size_t)row * DM;
    yr[tid]       = __float2bfloat16(d0 * rstd * g[tid]       + bta[tid]);
    yr[tid + 256] = __float2bfloat16(d1 * rstd * g[tid + 256] + bta[tid + 256]);
}

// ---------- deproj GEMM (fp32) writing d_out dtype-adaptively ----------
__global__ __launch_bounds__(256) void gemm_out(const float* __restrict__ A,
                                                const float* __restrict__ B,
                                                const float* __restrict__ bias,
                                                const int* __restrict__ cnt,
                                                void* __restrict__ dout,
                                                int M, int N, int K) {
    __shared__ float As[32][33];
    __shared__ float Bs[32][33];
    int tid = threadIdx.x;
    int tx = tid & 15, ty = tid >> 4;
    int m0 = blockIdx.x * 32, n0 = blockIdx.y * 32;
    float c[2][2] = {};
    for (int k0 = 0; k0 < K; k0 += 32) {
#pragma unroll
        for (int i = 0; i < 4; i++) {
            int idx = i * 256 + tid;
            int r = idx >> 5, kk = idx & 31;
            int gm = m0 + r;
            As[r][kk] = (gm < M) ? A[(size_t)gm * K + k0 + kk] : 0.f;
            Bs[r][kk] = B[(size_t)(n0 + r) * K + k0 + kk];
        }
        __syncthreads();
#pragma unroll
        for (int k = 0; k < 32; k++) {
            float a0 = As[ty * 2][k], a1 = As[ty * 2 + 1][k];
            float b0 = Bs[tx * 2][k], b1 = Bs[tx * 2 + 1][k];
            c[0][0] += a0 * b0; c[0][1] += a0 * b1;
            c[1][0] += a1 * b0; c[1][1] += a1 * b1;
        }
        __syncthreads();
    }
    bool isb = (*cnt == 0);
#pragma unroll
    for (int i = 0; i < 2; i++) {
        int m = m0 + ty * 2 + i;
        if (m >= M) continue;
#pragma unroll
        for (int jj = 0; jj < 2; jj++) {
            int n = n0 + tx * 2 + jj;
            float v = c[i][jj] + bias[n];
            if (isb) ((bf16*)dout)[(size_t)m * N + n] = __float2bfloat16(v);
            else     ((float*)dout)[(size_t)m * N + n] = v;
        }
    }
}

// ---------- unified MFMA bf16 NT GEMM, BM(M) x NT(N) tile ----------
template <int BM, int NT, int ROUTE, int ACT, bool OUT_BF16>
__global__ __launch_bounds__(256) void mfma_big(const bf16* __restrict__ A,
                                                const bf16* __restrict__ B,
                                                const float* __restrict__ bias,
                                                const float* __restrict__ resid,
                                                float* __restrict__ Cf,
                                                bf16* __restrict__ Cb,
                                                int M, int N, int K,
                                                size_t wstride, int bstride,
                                                size_t ostride) {
    __shared__ __align__(16) short Asm[BM * 40];
    __shared__ __align__(16) short Bsm[NT * 40];
    int tid = threadIdx.x, wave = tid >> 6, lane = tid & 63;
    int q = lane >> 4, l15 = lane & 15;
    int m0 = blockIdx.x * BM, n0 = blockIdx.y * NT;
    int lrow = tid >> 2, lk = (tid & 3) * 8;
    constexpr int MF = (NT == 128) ? (BM / 16) : (BM / 32);
    int m0w = (NT == 128) ? 0 : ((wave >> 1) * (BM / 2));
    int nfb = (NT == 128) ? (wave * 32) : ((wave & 1) * 32);
    floatx4 acc[MF][2] = {};
    for (int k0 = 0; k0 < K; k0 += 32) {
#pragma unroll
        for (int hh = 0; hh < BM / 64; hh++) {
            int row = lrow + hh * 64, gm = m0 + row;
            uint4 v = make_uint4(0u, 0u, 0u, 0u);
            if (gm < M) v = *(const uint4*)(A + (size_t)gm * K + k0 + lk);
            *(uint4*)(Asm + row * 40 + lk) = v;
        }
#pragma unroll
        for (int hh = 0; hh < NT / 64; hh++) {
            int row = lrow + hh * 64, gn = n0 + row;
            const bf16* src = ROUTE
                ? B + (size_t)(gn >> 9) * wstride + (size_t)(gn & 511) * K + k0 + lk
                : B + (size_t)gn * K + k0 + lk;
            *(uint4*)(Bsm + row * 40 + lk) = *(const uint4*)src;
        }
        __syncthreads();
        short8 a[MF], b2[2];
#pragma unroll
        for (int im = 0; im < MF; im++)
            a[im] = *(const short8*)(Asm + (m0w + im * 16 + l15) * 40 + q * 8);
#pragma unroll
        for (int jn = 0; jn < 2; jn++)
            b2[jn] = *(const short8*)(Bsm + (nfb + jn * 16 + l15) * 40 + q * 8);
#pragma unroll
        for (int im = 0; im < MF; im++)
#pragma unroll
            for (int jn = 0; jn < 2; jn++)
                acc[im][jn] = __builtin_amdgcn_mfma_f32_16x16x32_bf16(
                    a[im], b2[jn], acc[im][jn], 0, 0, 0);
        __syncthreads();
    }
#pragma unroll
    for (int im = 0; im < MF; im++) {
#pragma unroll
        for (int jn = 0; jn < 2; jn++) {
            int nn = n0 + nfb + jn * 16 + l15;
            float bval = ROUTE ? bias[(nn >> 9) * bstride + (nn & 511)] : bias[nn];
#pragma unroll
            for (int r = 0; r < 4; r++) {
                int m = m0 + m0w + im * 16 + q * 4 + r;
                if (m >= M) continue;
                float v = acc[im][jn][r] + bval;
                if (resid) v += resid[(size_t)m * N + nn];
                if (ACT == 1) v = fmaxf(v, 0.f);
                if (ROUTE)
                    Cb[(size_t)(nn >> 9) * ostride + (size_t)m * 512 + (nn & 511)] =
                        __float2bfloat16(v);
                else if (OUT_BF16)
                    Cb[(size_t)m * N + nn] = __float2bfloat16(v);
                else
                    Cf[(size_t)m * N + nn] = v;
            }
        }
    }
}

// ---------- V transpose: Vb[b,t,h*64+d] -> Vt[z][d][t] (stride 1024, zero-pad) ----
__global__ __launch_bounds__(256) void vt_k(const bf16* __restrict__ Vb,
                                            bf16* __restrict__ Vt) {
    __shared__ short tile[64][65];
    int t0 = blockIdx.x * 64, z = blockIdx.y;
    int b = z >> 3, h = z & 7;
    int tid = threadIdx.x;
#pragma unroll
    for (int i = 0; i < 16; i++) {
        int tr = i * 4 + (tid >> 6), d = tid & 63;
        int t = t0 + tr;
        bf16 v = (t < TT) ? Vb[((size_t)b * TT + t) * DM + h * 64 + d] : (bf16)__float2bfloat16(0.f);
        tile[tr][d] = *(short*)&v;
    }
    __syncthreads();
#pragma unroll
    for (int i = 0; i < 16; i++) {
        int dr = i * 4 + (tid >> 6), tc = tid & 63;
        *(short*)&Vt[(size_t)z * 65536 + dr * 1024 + t0 + tc] = tile[tc][dr];
    }
}

// ---------- fused attention (R5 structure + T5 setprio — measured optimum) --------
// KVBLK=128, 2 blocks/CU. R15's KVBLK=64 retile regressed (82us): grid is only
// 512 blocks = 2/CU available, so LDS headroom for a 3rd block bought nothing
// while barriers doubled. Reverted to the 69.6us configuration.
__global__ __launch_bounds__(256, 2) void attn_fused(const bf16* __restrict__ Q,
                                                     const bf16* __restrict__ K,
                                                     const bf16* __restrict__ Er,
                                                     const bf16* __restrict__ Vt,
                                                     bf16* __restrict__ AO) {
    __shared__ __align__(16) short Qs[6400];      // [2 kh][80][40]
    __shared__ __align__(16) short pool[13000];   // K 128x40 @0 + E 192x40 @5120; G 65x200 overlay
    __shared__ __align__(16) short Pl[64 * 136];  // P chunk (bf16)
    __shared__ __align__(16) short Vs[64 * 136];  // V chunk (d-major)
    __shared__ float rsw[4][64];
    int tid = threadIdx.x, wave = tid >> 6, lane = tid & 63;
    int q = lane >> 4, l15 = lane & 15;
    int m0 = blockIdx.x * 64;
    int z = blockIdx.z, b = z >> 3, h = z & 7;
    const bf16* Ap = Q + (size_t)b * TT * DM + h * 64;
    const bf16* Bp = K + (size_t)b * TT * DM + h * 64;
    const bf16* Vp = Vt + (size_t)z * 65536;
    int lrow = tid >> 2, lk = (tid & 3) * 8;
    int mw = wave * 16;

    // stage Q rows m0..m0+79, both 32-depth halves (persistent)
#pragma unroll
    for (int kh = 0; kh < 2; kh++) {
        int gm = m0 + lrow;
        uint4 v = make_uint4(0u, 0u, 0u, 0u);
        if (gm < TT) v = *(const uint4*)(Ap + (size_t)gm * DM + kh * 32 + lk);
        *(uint4*)(Qs + kh * 3200 + lrow * 40 + lk) = v;
        if (tid < 64) {
            int rr = 64 + (tid >> 2);
            int g2 = m0 + rr;
            uint4 v2 = make_uint4(0u, 0u, 0u, 0u);
            if (g2 < TT) v2 = *(const uint4*)(Ap + (size_t)g2 * DM + kh * 32 + lk);
            *(uint4*)(Qs + kh * 3200 + rr * 40 + lk) = v2;
        }
    }

    float rsum[16];
#pragma unroll
    for (int i = 0; i < 16; i++) rsum[i] = 0.f;
    floatx4 accO[4] = {};

    for (int tc = 0; tc < 8; tc++) {
        int t0 = tc * 128;
        int db = t0 - m0 - 64;
        floatx4 accS[4][2] = {};
        floatx4 accG[5][3] = {};
        for (int k0 = 0; k0 < 64; k0 += 32) {
            {   // K-half: 128 rows x 32
                int gn = t0 + lrow;
                uint4 v0 = make_uint4(0u, 0u, 0u, 0u), v1 = v0;
                if (gn < TT)      v0 = *(const uint4*)(Bp + (size_t)gn * DM + k0 + lk);
                if (gn + 64 < TT) v1 = *(const uint4*)(Bp + (size_t)(gn + 64) * DM + k0 + lk);
                *(uint4*)(pool + lrow * 40 + lk) = v0;
                *(uint4*)(pool + (lrow + 64) * 40 + lk) = v1;
            }
            {   // E-half: 192 rows x 32 (shift-gathered Er'')
#pragma unroll
                for (int hh = 0; hh < 3; hh++) {
                    int dd = lrow + hh * 64;
                    int dl = db + dd;
                    int src = (dl <= 0) ? (999 + dl) : (dl - 1);
                    uint4 v = make_uint4(0u, 0u, 0u, 0u);
                    if (src >= 0 && src < TT)
                        v = *(const uint4*)(Er + (size_t)src * 64 + k0 + lk);
                    *(uint4*)(pool + 5120 + dd * 40 + lk) = v;
                }
            }
            if (k0 == 0) {  // V chunk: 64 d-rows x 128 t-cols, 8 shorts/store
#pragma unroll
                for (int e = 0; e < 4; e++) {
                    int li = tid + e * 256;
                    int row = li >> 4, cs = (li & 15) * 8;
                    *(uint4*)(Vs + row * 136 + cs) =
                        *(const uint4*)(Vp + (size_t)row * 1024 + t0 + cs);
                }
            }
            __syncthreads();
            short8 a[5], bk[2], e[3];
#pragma unroll
            for (int im = 0; im < 5; im++)
                a[im] = *(const short8*)(Qs + (k0 >> 5) * 3200 + (im * 16 + l15) * 40 + q * 8);
#pragma unroll
            for (int jn = 0; jn < 2; jn++)
                bk[jn] = *(const short8*)(pool + (wave * 32 + jn * 16 + l15) * 40 + q * 8);
#pragma unroll
            for (int jg = 0; jg < 3; jg++)
                e[jg] = *(const short8*)(pool + 5120 + (wave * 48 + jg * 16 + l15) * 40 + q * 8);
            __builtin_amdgcn_s_setprio(1);
#pragma unroll
            for (int im = 0; im < 4; im++)
#pragma unroll
                for (int jn = 0; jn < 2; jn++)
                    accS[im][jn] = __builtin_amdgcn_mfma_f32_16x16x32_bf16(
                        a[im], bk[jn], accS[im][jn], 0, 0, 0);
#pragma unroll
            for (int im = 0; im < 5; im++)
#pragma unroll
                for (int jg = 0; jg < 3; jg++)
                    accG[im][jg] = __builtin_amdgcn_mfma_f32_16x16x32_bf16(
                        a[im], e[jg], accG[im][jg], 0, 0, 0);
            __builtin_amdgcn_s_setprio(0);
            __syncthreads();
        }
        // write G rows 0..64 to LDS (overlay pool) as bf16
#pragma unroll
        for (int im = 0; im < 5; im++)
#pragma unroll
            for (int jg = 0; jg < 3; jg++) {
                int col = wave * 48 + jg * 16 + l15;
#pragma unroll
                for (int r = 0; r < 4; r++) {
                    int row = im * 16 + q * 4 + r;
                    if (row < 65) {
                        bf16 gv = __float2bfloat16(accG[im][jg][r]);
                        pool[row * 200 + col] = *(short*)&gv;
                    }
                }
            }
        __syncthreads();
        // epilogue: rel gather + exp + rowsum + P write
#pragma unroll
        for (int im = 0; im < 4; im++)
#pragma unroll
            for (int jn = 0; jn < 2; jn++) {
                int nl = wave * 32 + jn * 16 + l15;
                int n = t0 + nl;
#pragma unroll
                for (int r = 0; r < 4; r++) {
                    int ml = im * 16 + q * 4 + r;
                    int m = m0 + ml;
                    float pe = 0.f;
                    if (n < TT) {
                        float rel = 0.f;
                        if (n != m + 1) {
                            int u = (n <= m) ? m : (m + 1);
                            int dd = n - u - db;
                            short gs = pool[(u - m0) * 200 + dd];
                            rel = __bfloat162float(*(bf16*)&gs);
                        }
                        pe = __expf((accS[im][jn][r] + rel) * 0.125f - PSHIFT);
                        rsum[im * 4 + r] += pe;
                    }
                    bf16 pb = __float2bfloat16(pe);
                    Pl[ml * 136 + nl] = *(short*)&pb;
                }
            }
        __syncthreads();
        // PV: each wave owns m-rows mw..mw+15, all 64 d-cols
        __builtin_amdgcn_s_setprio(1);
#pragma unroll
        for (int kc = 0; kc < 4; kc++) {
            short8 a = *(const short8*)(Pl + (mw + l15) * 136 + kc * 32 + q * 8);
#pragma unroll
            for (int jn = 0; jn < 4; jn++) {
                short8 bv = *(const short8*)(Vs + (jn * 16 + l15) * 136 + kc * 32 + q * 8);
                accO[jn] = __builtin_amdgcn_mfma_f32_16x16x32_bf16(a, bv, accO[jn], 0, 0, 0);
            }
        }
        __builtin_amdgcn_s_setprio(0);
        __syncthreads();
    }
    // rowsum: butterfly over the 16 l15 lanes, then sum 4 waves via LDS
#pragma unroll
    for (int t = 0; t < 16; t++) {
        float s = rsum[t];
        s += __shfl_xor(s, 1, 64); s += __shfl_xor(s, 2, 64);
        s += __shfl_xor(s, 4, 64); s += __shfl_xor(s, 8, 64);
        if (l15 == 0) rsw[wave][(t >> 2) * 16 + q * 4 + (t & 3)] = s;
    }
    __syncthreads();
#pragma unroll
    for (int r = 0; r < 4; r++) {
        int lm = mw + q * 4 + r;
        int m = m0 + lm;
        if (m >= TT) continue;
        float tot = rsw[0][lm] + rsw[1][lm] + rsw[2][lm] + rsw[3][lm];
        float inv = 1.f / tot;
#pragma unroll
        for (int jn = 0; jn < 4; jn++)
            AO[((size_t)b * TT + m) * DM + h * 64 + jn * 16 + l15] =
                __float2bfloat16(accO[jn][r] * inv);
    }
}

// ---------- launch ----------
extern "C" void kernel_launch(void* const* d_in, const int* in_sizes, int n_in,
                              void* d_out, int out_size, void* d_ws, size_t ws_size,
                              hipStream_t stream) {
    if (!g_arena) (void)hipMalloc(&g_arena, ARENA_BYTES);
    float* A = (float*)g_arena;

    static const unsigned off[27] = {
        0, 784000, 784800, 784832, 836032, 836096, 868864, 869376, 871424,
        873472, 1922048, 2970624, 4019200, 5067776, 5069824, 5071872,
        5073920, 5075968, 5331968, 5334016, 5336064, 9530368, 9538560,
        13732864, 13734912, 13800448, 13800576};
    const float* spec  = A + off[0];
    const float* c1w   = A + off[1];
    const float* c1b   = A + off[2];
    const float* c2b   = A + off[4];
    const float* projb = A + off[6];
    const float* ln1g  = A + off[7];
    const float* ln1b  = A + off[8];
    const float* qb    = A + off[13];
    const float* db    = A + off[16];
    const float* ln2g  = A + off[18];
    const float* ln2b  = A + off[19];
    const float* f1b   = A + off[21];
    const float* f2b_  = A + off[23];
    const float* depw  = A + off[24];
    const float* depb  = A + off[25];

    const size_t PA = 13800576;
    float* x    = A + PA;
    float* P1   = x + 2048000;               // hosts P1c (bf16)
    float* SM   = P1 + 1792000;
    bf16* P1c     = (bf16*)P1;               // [4,14,1000,32] bf16
    bf16* p2t_b   = (bf16*)SM;
    bf16* projw_b = (bf16*)(SM + 128000);
    bf16* w2p     = (bf16*)(SM + 150000);    // [64][800] permuted conv2 weights
    int*   cnt  = (int*)(SM + 256000);
    float* ScF  = SM + 256004;               // scratch region
    float* B0   = ScF + 32000000;
    bf16* wb_qkvd = (bf16*)B0;
    bf16* wb_f1   = (bf16*)(B0 + 2097152);
    bf16* wb_f2   = (bf16*)(B0 + 4194304);
    bf16* Erb     = (bf16*)(B0 + 6291456);
    bf16* xn_b    = (bf16*)(B0 + 6419456);
    bf16* AO_b    = (bf16*)(B0 + 7443456);
    bf16* Qb_b    = (bf16*)(B0 + 8467456);
    bf16* Kb_b    = (bf16*)(B0 + 9491456);
    bf16* Vb_b    = (bf16*)(B0 + 10515456);
    bf16* FFH_b   = (bf16*)(B0 + 11539456);
    bf16* Vt      = (bf16*)(B0 + 15635456);
    bf16* convout = (bf16*)(B0 + 16684032);  // pre-loop scratch [56000,64]

    hipMemsetAsync(cnt, 0, sizeof(int), stream);
    sniff_k<<<1024, 256, 0, stream>>>((const unsigned short*)d_in[20], 1000000, cnt);

    // compact fp32-copy table: only the tensors that actually get copied.
    static const int cvt_ids[NCVT] = {0, 1, 2, 4, 6, 7, 8, 13, 14, 15, 16,
                                      18, 19, 21, 23, 24, 25};
    CvtArgs ca;
    unsigned cum = 0;
    for (int t = 0; t < NCVT; t++) {
        int w = cvt_ids[t];
        ca.src[t] = d_in[w];
        ca.dst[t] = off[w];
        ca.cum[t] = cum;
        cum += off[w + 1] - off[w];
    }
    ca.cum[NCVT] = cum;   // 877,696
    ca.cnt = cnt; ca.dstA = A;
    cvt_all<<<(cum + 255) / 256, 256, 0, stream>>>(ca);

    // big weights: straight dtype-adaptive downcast from d_in
    for (int t = 0; t < 4; t++)
        f2bf_dyn<<<4096, 256, 0, stream>>>(d_in[9 + t], wb_qkvd + (size_t)t * 1048576,
                                           1048576, cnt);
    f2bf_dyn<<<16384, 256, 0, stream>>>(d_in[20], wb_f1, 4194304, cnt);
    f2bf_dyn<<<16384, 256, 0, stream>>>(d_in[22], wb_f2, 4194304, cnt);
    f2bf_dyn<<<1000,  256, 0, stream>>>(d_in[17], Erb,   256000, cnt);
    f2bf_dyn<<<128,   256, 0, stream>>>(d_in[5],  projw_b, 32768, cnt);
    w2perm<<<200, 256, 0, stream>>>(d_in[3], w2p, cnt);

    // conv frontend (implicit-GEMM conv2; no im2col)
    conv1_pool2<<<dim3(4, 14, 16), 256, 0, stream>>>(spec, c1w, c1b, P1c);
    conv2_gemm<<<dim3(16, 14, 4), 256, 0, stream>>>(P1c, w2p, c2b, convout);
    pool2_k<<<1000, 256, 0, stream>>>(convout, p2t_b);
    mfma_big<64, 64, 0, 0, false><<<dim3(63, 8), 256, 0, stream>>>(
        p2t_b, projw_b, projb, nullptr, x, nullptr, BT, DM, 64, 0, 0, 0);

    for (int l = 0; l < LL; l++) {
        layernorm_k<<<BT, 256, 0, stream>>>(x, ln1g + l * DM, ln1b + l * DM, xn_b);
        mfma_big<64, 128, 1, 0, true><<<dim3(63, 12), 256, 0, stream>>>(
            xn_b, wb_qkvd + (size_t)l * DM * DM, qb + l * DM, nullptr,
            nullptr, Qb_b, BT, 1536, DM, 1048576, 2048, 2048000);
        vt_k<<<dim3(16, 32), 256, 0, stream>>>(Vb_b, Vt);
        attn_fused<<<dim3(16, 1, 32), 256, 0, stream>>>(
            Qb_b, Kb_b, Erb + (size_t)l * TT * DEPTH, Vt, AO_b);
        mfma_big<64, 64, 0, 0, false><<<dim3(63, 8), 256, 0, stream>>>(
            AO_b, wb_qkvd + 3 * 1048576 + (size_t)l * DM * DM, db + l * DM, x,
            x, nullptr, BT, DM, DM, 0, 0, 0);
        layernorm_k<<<BT, 256, 0, stream>>>(x, ln2g + l * DM, ln2b + l * DM, xn_b);
        mfma_big<64, 128, 0, 1, true><<<dim3(63, 16), 256, 0, stream>>>(
            xn_b, wb_f1 + (size_t)l * FFN * DM, f1b + l * FFN, nullptr,
            nullptr, FFH_b, BT, FFN, DM, 0, 0, 0);
        mfma_big<64, 64, 0, 0, false><<<dim3(63, 8), 256, 0, stream>>>(
            FFH_b, wb_f2 + (size_t)l * DM * FFN, f2b_ + l * DM, x,
            x, nullptr, BT, DM, FFN, 0, 0, 0);
    }

    gemm_out<<<dim3(125, 4), 256, 0, stream>>>(x, depw, depb, cnt, d_out, BT, EDIM, DM);
}

// Round 18
// 1078.800 us; speedup vs baseline: 1.0588x; 1.0076x over previous
//
#include <hip/hip_runtime.h>
#include <hip/hip_bf16.h>
#include <hip/hip_fp16.h>
#include <math.h>

// ---------- constants ----------
#define BB 4
#define FBINS 196
#define TT 1000
#define DM 512
#define HH 8
#define DEPTH 64
#define FFN 2048
#define LL 4
#define EDIM 128
#define BT (BB*TT)   // 4000
#define PSHIFT 12.0f

typedef __hip_bfloat16 bf16;
typedef __attribute__((ext_vector_type(8))) short short8;
typedef __attribute__((ext_vector_type(4))) float floatx4;

// ---------- private arena ----------
#define ARENA_BYTES 420000000ULL
static void* g_arena = nullptr;
__attribute__((constructor)) static void arena_init() {
    if (!g_arena) (void)hipMalloc(&g_arena, ARENA_BYTES);
}

__device__ __forceinline__ float gelu_f(float x) {
    return 0.5f * x * (1.0f + erff(x * 0.70710678118654752440f));
}
// gelu is valley-shaped (decreasing then increasing, min at x~-0.7518), so
// max_i gelu(x_i) == max(gelu(min_i x_i), gelu(max_i x_i)) EXACTLY.

// ---------- dtype sniffer (cnt==0 <=> inputs are bf16) ----------
__global__ __launch_bounds__(256) void sniff_k(const unsigned short* __restrict__ p,
                                               int n, int* __restrict__ cnt) {
    int i = blockIdx.x * 256 + threadIdx.x;
    int c = 0;
    for (; i < n; i += gridDim.x * 256) {
        unsigned short u = p[i];
        if ((unsigned short)(u & 0x7FFF) > (unsigned short)0x7F80) c++;
    }
    if (c) atomicAdd(cnt, c);
}

// ---------- convert small fp32 params (compact: only tensors actually copied) ----
#define NCVT 17
struct CvtArgs {
    const void* src[NCVT];
    unsigned dst[NCVT];       // dst offset (floats) in arena
    unsigned cum[NCVT + 1];   // cumulative element counts
    const int* cnt;
    float* dstA;
};
__global__ __launch_bounds__(256) void cvt_all(CvtArgs a) {
    unsigned i = blockIdx.x * 256 + threadIdx.x;
    if (i >= a.cum[NCVT]) return;
    bool isb = (*a.cnt == 0);
    int w = 0;
    while (i >= a.cum[w + 1]) w++;
    unsigned j = i - a.cum[w];
    float v = isb ? __bfloat162float(((const bf16*)a.src[w])[j])
                  : ((const float*)a.src[w])[j];
    a.dstA[a.dst[w] + j] = v;
}

// ---------- dtype-adaptive downcast straight from d_in ----------
__global__ __launch_bounds__(256) void f2bf_dyn(const void* __restrict__ src,
                                                bf16* __restrict__ d, int n,
                                                const int* __restrict__ cnt) {
    int i = blockIdx.x * 256 + threadIdx.x;
    if (i >= n) return;
    if (*cnt == 0) d[i] = ((const bf16*)src)[i];
    else           d[i] = __float2bfloat16(((const float*)src)[i]);
}

// ---------- conv2 weight permute: [c][ci][di][dj] -> [c][(di*5+dj)*32+ci] bf16 ----
__global__ __launch_bounds__(256) void w2perm(const void* __restrict__ src,
                                              bf16* __restrict__ d,
                                              const int* __restrict__ cnt) {
    int idx = blockIdx.x * 256 + threadIdx.x;
    if (idx >= 51200) return;
    int c = idx / 800, k = idx - c * 800;
    int kc = k >> 5, ci = k & 31;
    int di = kc / 5, dj = kc - di * 5;
    int s = ((c * 32 + ci) * 5 + di) * 5 + dj;
    float v = (*cnt == 0) ? __bfloat162float(((const bf16*)src)[s])
                          : ((const float*)src)[s];
    d[idx] = __float2bfloat16(v);
}

// ---------- conv1 + gelu + maxpool(14), LDS-tiled, channel-last bf16 out ----------
__global__ __launch_bounds__(256) void conv1_pool2(const float* __restrict__ spec,
                                                   const float* __restrict__ w1,
                                                   const float* __restrict__ b1,
                                                   bf16* __restrict__ P1c) {
    __shared__ float ss[18][256];
    __shared__ float sw[200];
    int jt = blockIdx.x, p = blockIdx.y, z = blockIdx.z;
    int b = z >> 2, cg = z & 3;
    int tid = threadIdx.x;
    for (int i = tid; i < 200; i += 256) sw[i] = w1[cg * 200 + i];
    int ibase = p * 14, c0 = jt * 250 - 2;
    for (int idx = tid; idx < 18 * 256; idx += 256) {
        int rr = idx >> 8, cc = idx & 255;
        int gi = ibase - 2 + rr, gj = c0 + cc;
        ss[rr][cc] = (gi >= 0 && gi < FBINS && gj >= 0 && gj < TT && cc < 254)
                         ? spec[(size_t)b * FBINS * TT + (size_t)gi * TT + gj] : 0.f;
    }
    __syncthreads();
    if (tid >= 250) return;
    int j = jt * 250 + tid;
    unsigned short* orow = (unsigned short*)P1c + ((size_t)((b * 14 + p) * 1000 + j)) * 32;
    for (int cpl = 0; cpl < 8; cpl += 2) {
        int cp = cg * 8 + cpl;
        float conv[2][14];
        float b0 = b1[cp], b1v = b1[cp + 1];
#pragma unroll
        for (int i = 0; i < 14; i++) { conv[0][i] = b0; conv[1][i] = b1v; }
        const float* w0 = sw + cpl * 25;
        const float* w1p = sw + (cpl + 1) * 25;
        for (int rr = 0; rr < 18; rr++) {
            float v0 = ss[rr][tid], v1 = ss[rr][tid + 1], v2 = ss[rr][tid + 2],
                  v3 = ss[rr][tid + 3], v4 = ss[rr][tid + 4];
#pragma unroll
            for (int di = 0; di < 5; di++) {
                int i = rr - di;
                if (i >= 0 && i < 14) {
                    conv[0][i] += v0 * w0[di * 5] + v1 * w0[di * 5 + 1] + v2 * w0[di * 5 + 2]
                                + v3 * w0[di * 5 + 3] + v4 * w0[di * 5 + 4];
                    conv[1][i] += v0 * w1p[di * 5] + v1 * w1p[di * 5 + 1] + v2 * w1p[di * 5 + 2]
                                + v3 * w1p[di * 5 + 3] + v4 * w1p[di * 5 + 4];
                }
            }
        }
        float mx0 = -1e30f, mn0 = 1e30f, mx1 = -1e30f, mn1 = 1e30f;
#pragma unroll
        for (int i = 0; i < 14; i++) {
            mx0 = fmaxf(mx0, conv[0][i]); mn0 = fminf(mn0, conv[0][i]);
            mx1 = fmaxf(mx1, conv[1][i]); mn1 = fminf(mn1, conv[1][i]);
        }
        float m0 = fmaxf(gelu_f(mx0), gelu_f(mn0));
        float m1 = fmaxf(gelu_f(mx1), gelu_f(mn1));
        bf16 mb0 = __float2bfloat16(m0), mb1 = __float2bfloat16(m1);
        unsigned pk = ((unsigned)(*(unsigned short*)&mb1) << 16) |
                      (unsigned)(*(unsigned short*)&mb0);
        *(unsigned*)(orow + cp) = pk;
    }
}

// ---------- conv2 implicit-GEMM ----------
__global__ __launch_bounds__(256) void conv2_gemm(const bf16* __restrict__ P1c,
                                                  const bf16* __restrict__ W2p,
                                                  const float* __restrict__ c2b,
                                                  bf16* __restrict__ convout) {
    __shared__ __align__(16) short Asm[64 * 40];
    __shared__ __align__(16) short Bsm[64 * 40];
    int tid = threadIdx.x, wave = tid >> 6, lane = tid & 63;
    int q = lane >> 4, l15 = lane & 15;
    int jt = blockIdx.x, i = blockIdx.y, b = blockIdx.z;
    int lrow = tid >> 2, lci = (tid & 3) * 8;
    int jrow = jt * 64 + lrow;
    int mw = (wave & 1) * 32, nw = (wave >> 1) * 32;
    floatx4 acc[2][2] = {};
    for (int di = 0; di < 5; di++) {
        int ii = i + di - 2;
        bool iok = (ii >= 0 && ii < 14);
        for (int dj = 0; dj < 5; dj++) {
            int kc = di * 5 + dj;
            {
                int jj = jrow + dj - 2;
                uint4 v = make_uint4(0u, 0u, 0u, 0u);
                if (iok && jrow < TT && jj >= 0 && jj < TT)
                    v = *(const uint4*)(P1c +
                        (((size_t)(b * 14 + ii)) * TT + jj) * 32 + lci);
                *(uint4*)(Asm + lrow * 40 + lci) = v;
            }
            {
                *(uint4*)(Bsm + lrow * 40 + lci) =
                    *(const uint4*)(W2p + (size_t)lrow * 800 + kc * 32 + lci);
            }
            __syncthreads();
            short8 a0 = *(const short8*)(Asm + (mw + l15) * 40 + q * 8);
            short8 a1 = *(const short8*)(Asm + (mw + 16 + l15) * 40 + q * 8);
            short8 b0 = *(const short8*)(Bsm + (nw + l15) * 40 + q * 8);
            short8 b1 = *(const short8*)(Bsm + (nw + 16 + l15) * 40 + q * 8);
            acc[0][0] = __builtin_amdgcn_mfma_f32_16x16x32_bf16(a0, b0, acc[0][0], 0, 0, 0);
            acc[0][1] = __builtin_amdgcn_mfma_f32_16x16x32_bf16(a0, b1, acc[0][1], 0, 0, 0);
            acc[1][0] = __builtin_amdgcn_mfma_f32_16x16x32_bf16(a1, b0, acc[1][0], 0, 0, 0);
            acc[1][1] = __builtin_amdgcn_mfma_f32_16x16x32_bf16(a1, b1, acc[1][1], 0, 0, 0);
            __syncthreads();
        }
    }
#pragma unroll
    for (int im = 0; im < 2; im++) {
#pragma unroll
        for (int jn = 0; jn < 2; jn++) {
            int c = nw + jn * 16 + l15;
            float bv = c2b[c];
#pragma unroll
            for (int r = 0; r < 4; r++) {
                int j = jt * 64 + mw + im * 16 + q * 4 + r;
                if (j >= TT) continue;
                convout[((size_t)(b * 14 + i) * TT + j) * 64 + c] =
                    __float2bfloat16(acc[im][jn][r] + bv);
            }
        }
    }
}

// ---------- conv2 epilogue: gelu + maxpool(14) + transpose (valley-trick) ----------
__global__ __launch_bounds__(256) void pool2_k(const bf16* __restrict__ convout,
                                               bf16* __restrict__ p2t) {
    int idx = blockIdx.x * 256 + threadIdx.x;
    if (idx >= 256000) return;
    int c = idx & 63, bj = idx >> 6;
    int b = bj / 1000, j = bj - b * 1000;
    float mx = -1e30f, mn = 1e30f;
#pragma unroll
    for (int i = 0; i < 14; i++) {
        float v = __bfloat162float(convout[((size_t)(b * 14 + i) * 1000 + j) * 64 + c]);
        mx = fmaxf(mx, v); mn = fminf(mn, v);
    }
    p2t[(size_t)bj * 64 + c] = __float2bfloat16(fmaxf(gelu_f(mx), gelu_f(mn)));
}

// ---------- layernorm: fp32 in -> bf16 out (wave-shuffle reduce, 2 barriers) ------
// Was: LDS tree with ~18 __syncthreads per block (2 passes x 8 halvings) — the
// kernel cost was barrier serialization, not its 12 MB of traffic. Now: per-wave
// __shfl_xor reduce (6 steps, no barrier) + one 4-float LDS exchange per pass.
__global__ __launch_bounds__(256) void layernorm_k(const float* __restrict__ x,
                                                   const float* __restrict__ g,
                                                   const float* __restrict__ bta,
                                                   bf16* __restrict__ y) {
    __shared__ float red1[4], red2[4];
    int row = blockIdx.x, tid = threadIdx.x;
    int wave = tid >> 6, lane = tid & 63;
    const float* xr = x + (size_t)row * DM;
    float v0 = xr[tid], v1 = xr[tid + 256];
    float s = v0 + v1;
    s += __shfl_xor(s, 1, 64);  s += __shfl_xor(s, 2, 64);
    s += __shfl_xor(s, 4, 64);  s += __shfl_xor(s, 8, 64);
    s += __shfl_xor(s, 16, 64); s += __shfl_xor(s, 32, 64);
    if (lane == 0) red1[wave] = s;
    __syncthreads();
    float mu = (red1[0] + red1[1] + red1[2] + red1[3]) * (1.f / 512.f);
    float d0 = v0 - mu, d1 = v1 - mu;
    float sq = d0 * d0 + d1 * d1;
    sq += __shfl_xor(sq, 1, 64);  sq += __shfl_xor(sq, 2, 64);
    sq += __shfl_xor(sq, 4, 64);  sq += __shfl_xor(sq, 8, 64);
    sq += __shfl_xor(sq, 16, 64); sq += __shfl_xor(sq, 32, 64);
    if (lane == 0) red2[wave] = sq;
    __syncthreads();
    float rstd = rsqrtf((red2[0] + red2[1] + red2[2] + red2[3]) * (1.f / 512.f) + 1e-5f);
    bf16* yr = y + (size_t)row * DM;
    yr[tid]       = __float2bfloat16(d0 * rstd * g[tid]       + bta[tid]);
    yr[tid + 256] = __float2bfloat16(d1 * rstd * g[tid + 256] + bta[tid + 256]);
}

// ---------- deproj GEMM (fp32) writing d_out dtype-adaptively ----------
__global__ __launch_bounds__(256) void gemm_out(const float* __restrict__ A,
                                                const float* __restrict__ B,
                                                const float* __restrict__ bias,
                                                const int* __restrict__ cnt,
                                                void* __restrict__ dout,
                                                int M, int N, int K) {
    __shared__ float As[32][33];
    __shared__ float Bs[32][33];
    int tid = threadIdx.x;
    int tx = tid & 15, ty = tid >> 4;
    int m0 = blockIdx.x * 32, n0 = blockIdx.y * 32;
    float c[2][2] = {};
    for (int k0 = 0; k0 < K; k0 += 32) {
#pragma unroll
        for (int i = 0; i < 4; i++) {
            int idx = i * 256 + tid;
            int r = idx >> 5, kk = idx & 31;
            int gm = m0 + r;
            As[r][kk] = (gm < M) ? A[(size_t)gm * K + k0 + kk] : 0.f;
            Bs[r][kk] = B[(size_t)(n0 + r) * K + k0 + kk];
        }
        __syncthreads();
#pragma unroll
        for (int k = 0; k < 32; k++) {
            float a0 = As[ty * 2][k], a1 = As[ty * 2 + 1][k];
            float b0 = Bs[tx * 2][k], b1 = Bs[tx * 2 + 1][k];
            c[0][0] += a0 * b0; c[0][1] += a0 * b1;
            c[1][0] += a1 * b0; c[1][1] += a1 * b1;
        }
        __syncthreads();
    }
    bool isb = (*cnt == 0);
#pragma unroll
    for (int i = 0; i < 2; i++) {
        int m = m0 + ty * 2 + i;
        if (m >= M) continue;
#pragma unroll
        for (int jj = 0; jj < 2; jj++) {
            int n = n0 + tx * 2 + jj;
            float v = c[i][jj] + bias[n];
            if (isb) ((bf16*)dout)[(size_t)m * N + n] = __float2bfloat16(v);
            else     ((float*)dout)[(size_t)m * N + n] = v;
        }
    }
}

// ---------- unified MFMA bf16 NT GEMM, BM(M) x NT(N) tile ----------
template <int BM, int NT, int ROUTE, int ACT, bool OUT_BF16>
__global__ __launch_bounds__(256) void mfma_big(const bf16* __restrict__ A,
                                                const bf16* __restrict__ B,
                                                const float* __restrict__ bias,
                                                const float* __restrict__ resid,
                                                float* __restrict__ Cf,
                                                bf16* __restrict__ Cb,
                                                int M, int N, int K,
                                                size_t wstride, int bstride,
                                                size_t ostride) {
    __shared__ __align__(16) short Asm[BM * 40];
    __shared__ __align__(16) short Bsm[NT * 40];
    int tid = threadIdx.x, wave = tid >> 6, lane = tid & 63;
    int q = lane >> 4, l15 = lane & 15;
    int m0 = blockIdx.x * BM, n0 = blockIdx.y * NT;
    int lrow = tid >> 2, lk = (tid & 3) * 8;
    constexpr int MF = (NT == 128) ? (BM / 16) : (BM / 32);
    int m0w = (NT == 128) ? 0 : ((wave >> 1) * (BM / 2));
    int nfb = (NT == 128) ? (wave * 32) : ((wave & 1) * 32);
    floatx4 acc[MF][2] = {};
    for (int k0 = 0; k0 < K; k0 += 32) {
#pragma unroll
        for (int hh = 0; hh < BM / 64; hh++) {
            int row = lrow + hh * 64, gm = m0 + row;
            uint4 v = make_uint4(0u, 0u, 0u, 0u);
            if (gm < M) v = *(const uint4*)(A + (size_t)gm * K + k0 + lk);
            *(uint4*)(Asm + row * 40 + lk) = v;
        }
#pragma unroll
        for (int hh = 0; hh < NT / 64; hh++) {
            int row = lrow + hh * 64, gn = n0 + row;
            const bf16* src = ROUTE
                ? B + (size_t)(gn >> 9) * wstride + (size_t)(gn & 511) * K + k0 + lk
                : B + (size_t)gn * K + k0 + lk;
            *(uint4*)(Bsm + row * 40 + lk) = *(const uint4*)src;
        }
        __syncthreads();
        short8 a[MF], b2[2];
#pragma unroll
        for (int im = 0; im < MF; im++)
            a[im] = *(const short8*)(Asm + (m0w + im * 16 + l15) * 40 + q * 8);
#pragma unroll
        for (int jn = 0; jn < 2; jn++)
            b2[jn] = *(const short8*)(Bsm + (nfb + jn * 16 + l15) * 40 + q * 8);
#pragma unroll
        for (int im = 0; im < MF; im++)
#pragma unroll
            for (int jn = 0; jn < 2; jn++)
                acc[im][jn] = __builtin_amdgcn_mfma_f32_16x16x32_bf16(
                    a[im], b2[jn], acc[im][jn], 0, 0, 0);
        __syncthreads();
    }
#pragma unroll
    for (int im = 0; im < MF; im++) {
#pragma unroll
        for (int jn = 0; jn < 2; jn++) {
            int nn = n0 + nfb + jn * 16 + l15;
            float bval = ROUTE ? bias[(nn >> 9) * bstride + (nn & 511)] : bias[nn];
#pragma unroll
            for (int r = 0; r < 4; r++) {
                int m = m0 + m0w + im * 16 + q * 4 + r;
                if (m >= M) continue;
                float v = acc[im][jn][r] + bval;
                if (resid) v += resid[(size_t)m * N + nn];
                if (ACT == 1) v = fmaxf(v, 0.f);
                if (ROUTE)
                    Cb[(size_t)(nn >> 9) * ostride + (size_t)m * 512 + (nn & 511)] =
                        __float2bfloat16(v);
                else if (OUT_BF16)
                    Cb[(size_t)m * N + nn] = __float2bfloat16(v);
                else
                    Cf[(size_t)m * N + nn] = v;
            }
        }
    }
}

// ---------- V transpose: Vb[b,t,h*64+d] -> Vt[z][d][t] (stride 1024, zero-pad) ----
__global__ __launch_bounds__(256) void vt_k(const bf16* __restrict__ Vb,
                                            bf16* __restrict__ Vt) {
    __shared__ short tile[64][65];
    int t0 = blockIdx.x * 64, z = blockIdx.y;
    int b = z >> 3, h = z & 7;
    int tid = threadIdx.x;
#pragma unroll
    for (int i = 0; i < 16; i++) {
        int tr = i * 4 + (tid >> 6), d = tid & 63;
        int t = t0 + tr;
        bf16 v = (t < TT) ? Vb[((size_t)b * TT + t) * DM + h * 64 + d] : (bf16)__float2bfloat16(0.f);
        tile[tr][d] = *(short*)&v;
    }
    __syncthreads();
#pragma unroll
    for (int i = 0; i < 16; i++) {
        int dr = i * 4 + (tid >> 6), tc = tid & 63;
        *(short*)&Vt[(size_t)z * 65536 + dr * 1024 + t0 + tc] = tile[tc][dr];
    }
}

// ---------- fused attention (R5 structure + T5 setprio — measured optimum) --------
__global__ __launch_bounds__(256, 2) void attn_fused(const bf16* __restrict__ Q,
                                                     const bf16* __restrict__ K,
                                                     const bf16* __restrict__ Er,
                                                     const bf16* __restrict__ Vt,
                                                     bf16* __restrict__ AO) {
    __shared__ __align__(16) short Qs[6400];      // [2 kh][80][40]
    __shared__ __align__(16) short pool[13000];   // K 128x40 @0 + E 192x40 @5120; G 65x200 overlay
    __shared__ __align__(16) short Pl[64 * 136];  // P chunk (bf16)
    __shared__ __align__(16) short Vs[64 * 136];  // V chunk (d-major)
    __shared__ float rsw[4][64];
    int tid = threadIdx.x, wave = tid >> 6, lane = tid & 63;
    int q = lane >> 4, l15 = lane & 15;
    int m0 = blockIdx.x * 64;
    int z = blockIdx.z, b = z >> 3, h = z & 7;
    const bf16* Ap = Q + (size_t)b * TT * DM + h * 64;
    const bf16* Bp = K + (size_t)b * TT * DM + h * 64;
    const bf16* Vp = Vt + (size_t)z * 65536;
    int lrow = tid >> 2, lk = (tid & 3) * 8;
    int mw = wave * 16;

    // stage Q rows m0..m0+79, both 32-depth halves (persistent)
#pragma unroll
    for (int kh = 0; kh < 2; kh++) {
        int gm = m0 + lrow;
        uint4 v = make_uint4(0u, 0u, 0u, 0u);
        if (gm < TT) v = *(const uint4*)(Ap + (size_t)gm * DM + kh * 32 + lk);
        *(uint4*)(Qs + kh * 3200 + lrow * 40 + lk) = v;
        if (tid < 64) {
            int rr = 64 + (tid >> 2);
            int g2 = m0 + rr;
            uint4 v2 = make_uint4(0u, 0u, 0u, 0u);
            if (g2 < TT) v2 = *(const uint4*)(Ap + (size_t)g2 * DM + kh * 32 + lk);
            *(uint4*)(Qs + kh * 3200 + rr * 40 + lk) = v2;
        }
    }

    float rsum[16];
#pragma unroll
    for (int i = 0; i < 16; i++) rsum[i] = 0.f;
    floatx4 accO[4] = {};

    for (int tc = 0; tc < 8; tc++) {
        int t0 = tc * 128;
        int db = t0 - m0 - 64;
        floatx4 accS[4][2] = {};
        floatx4 accG[5][3] = {};
        for (int k0 = 0; k0 < 64; k0 += 32) {
            {   // K-half: 128 rows x 32
                int gn = t0 + lrow;
                uint4 v0 = make_uint4(0u, 0u, 0u, 0u), v1 = v0;
                if (gn < TT)      v0 = *(const uint4*)(Bp + (size_t)gn * DM + k0 + lk);
                if (gn + 64 < TT) v1 = *(const uint4*)(Bp + (size_t)(gn + 64) * DM + k0 + lk);
                *(uint4*)(pool + lrow * 40 + lk) = v0;
                *(uint4*)(pool + (lrow + 64) * 40 + lk) = v1;
            }
            {   // E-half: 192 rows x 32 (shift-gathered Er'')
#pragma unroll
                for (int hh = 0; hh < 3; hh++) {
                    int dd = lrow + hh * 64;
                    int dl = db + dd;
                    int src = (dl <= 0) ? (999 + dl) : (dl - 1);
                    uint4 v = make_uint4(0u, 0u, 0u, 0u);
                    if (src >= 0 && src < TT)
                        v = *(const uint4*)(Er + (size_t)src * 64 + k0 + lk);
                    *(uint4*)(pool + 5120 + dd * 40 + lk) = v;
                }
            }
            if (k0 == 0) {  // V chunk: 64 d-rows x 128 t-cols, 8 shorts/store
#pragma unroll
                for (int e = 0; e < 4; e++) {
                    int li = tid + e * 256;
                    int row = li >> 4, cs = (li & 15) * 8;
                    *(uint4*)(Vs + row * 136 + cs) =
                        *(const uint4*)(Vp + (size_t)row * 1024 + t0 + cs);
                }
            }
            __syncthreads();
            short8 a[5], bk[2], e[3];
#pragma unroll
            for (int im = 0; im < 5; im++)
                a[im] = *(const short8*)(Qs + (k0 >> 5) * 3200 + (im * 16 + l15) * 40 + q * 8);
#pragma unroll
            for (int jn = 0; jn < 2; jn++)
                bk[jn] = *(const short8*)(pool + (wave * 32 + jn * 16 + l15) * 40 + q * 8);
#pragma unroll
            for (int jg = 0; jg < 3; jg++)
                e[jg] = *(const short8*)(pool + 5120 + (wave * 48 + jg * 16 + l15) * 40 + q * 8);
            __builtin_amdgcn_s_setprio(1);
#pragma unroll
            for (int im = 0; im < 4; im++)
#pragma unroll
                for (int jn = 0; jn < 2; jn++)
                    accS[im][jn] = __builtin_amdgcn_mfma_f32_16x16x32_bf16(
                        a[im], bk[jn], accS[im][jn], 0, 0, 0);
#pragma unroll
            for (int im = 0; im < 5; im++)
#pragma unroll
                for (int jg = 0; jg < 3; jg++)
                    accG[im][jg] = __builtin_amdgcn_mfma_f32_16x16x32_bf16(
                        a[im], e[jg], accG[im][jg], 0, 0, 0);
            __builtin_amdgcn_s_setprio(0);
            __syncthreads();
        }
        // write G rows 0..64 to LDS (overlay pool) as bf16
#pragma unroll
        for (int im = 0; im < 5; im++)
#pragma unroll
            for (int jg = 0; jg < 3; jg++) {
                int col = wave * 48 + jg * 16 + l15;
#pragma unroll
                for (int r = 0; r < 4; r++) {
                    int row = im * 16 + q * 4 + r;
                    if (row < 65) {
                        bf16 gv = __float2bfloat16(accG[im][jg][r]);
                        pool[row * 200 + col] = *(short*)&gv;
                    }
                }
            }
        __syncthreads();
        // epilogue: rel gather + exp + rowsum + P write
#pragma unroll
        for (int im = 0; im < 4; im++)
#pragma unroll
            for (int jn = 0; jn < 2; jn++) {
                int nl = wave * 32 + jn * 16 + l15;
                int n = t0 + nl;
#pragma unroll
                for (int r = 0; r < 4; r++) {
                    int ml = im * 16 + q * 4 + r;
                    int m = m0 + ml;
                    float pe = 0.f;
                    if (n < TT) {
                        float rel = 0.f;
                        if (n != m + 1) {
                            int u = (n <= m) ? m : (m + 1);
                            int dd = n - u - db;
                            short gs = pool[(u - m0) * 200 + dd];
                            rel = __bfloat162float(*(bf16*)&gs);
                        }
                        pe = __expf((accS[im][jn][r] + rel) * 0.125f - PSHIFT);
                        rsum[im * 4 + r] += pe;
                    }
                    bf16 pb = __float2bfloat16(pe);
                    Pl[ml * 136 + nl] = *(short*)&pb;
                }
            }
        __syncthreads();
        // PV: each wave owns m-rows mw..mw+15, all 64 d-cols
        __builtin_amdgcn_s_setprio(1);
#pragma unroll
        for (int kc = 0; kc < 4; kc++) {
            short8 a = *(const short8*)(Pl + (mw + l15) * 136 + kc * 32 + q * 8);
#pragma unroll
            for (int jn = 0; jn < 4; jn++) {
                short8 bv = *(const short8*)(Vs + (jn * 16 + l15) * 136 + kc * 32 + q * 8);
                accO[jn] = __builtin_amdgcn_mfma_f32_16x16x32_bf16(a, bv, accO[jn], 0, 0, 0);
            }
        }
        __builtin_amdgcn_s_setprio(0);
        __syncthreads();
    }
    // rowsum: butterfly over the 16 l15 lanes, then sum 4 waves via LDS
#pragma unroll
    for (int t = 0; t < 16; t++) {
        float s = rsum[t];
        s += __shfl_xor(s, 1, 64); s += __shfl_xor(s, 2, 64);
        s += __shfl_xor(s, 4, 64); s += __shfl_xor(s, 8, 64);
        if (l15 == 0) rsw[wave][(t >> 2) * 16 + q * 4 + (t & 3)] = s;
    }
    __syncthreads();
#pragma unroll
    for (int r = 0; r < 4; r++) {
        int lm = mw + q * 4 + r;
        int m = m0 + lm;
        if (m >= TT) continue;
        float tot = rsw[0][lm] + rsw[1][lm] + rsw[2][lm] + rsw[3][lm];
        float inv = 1.f / tot;
#pragma unroll
        for (int jn = 0; jn < 4; jn++)
            AO[((size_t)b * TT + m) * DM + h * 64 + jn * 16 + l15] =
                __float2bfloat16(accO[jn][r] * inv);
    }
}

// ---------- launch ----------
extern "C" void kernel_launch(void* const* d_in, const int* in_sizes, int n_in,
                              void* d_out, int out_size, void* d_ws, size_t ws_size,
                              hipStream_t stream) {
    if (!g_arena) (void)hipMalloc(&g_arena, ARENA_BYTES);
    float* A = (float*)g_arena;

    static const unsigned off[27] = {
        0, 784000, 784800, 784832, 836032, 836096, 868864, 869376, 871424,
        873472, 1922048, 2970624, 4019200, 5067776, 5069824, 5071872,
        5073920, 5075968, 5331968, 5334016, 5336064, 9530368, 9538560,
        13732864, 13734912, 13800448, 13800576};
    const float* spec  = A + off[0];
    const float* c1w   = A + off[1];
    const float* c1b   = A + off[2];
    const float* c2b   = A + off[4];
    const float* projb = A + off[6];
    const float* ln1g  = A + off[7];
    const float* ln1b  = A + off[8];
    const float* qb    = A + off[13];
    const float* db    = A + off[16];
    const float* ln2g  = A + off[18];
    const float* ln2b  = A + off[19];
    const float* f1b   = A + off[21];
    const float* f2b_  = A + off[23];
    const float* depw  = A + off[24];
    const float* depb  = A + off[25];

    const size_t PA = 13800576;
    float* x    = A + PA;
    float* P1   = x + 2048000;               // hosts P1c (bf16)
    float* SM   = P1 + 1792000;
    bf16* P1c     = (bf16*)P1;               // [4,14,1000,32] bf16
    bf16* p2t_b   = (bf16*)SM;
    bf16* projw_b = (bf16*)(SM + 128000);
    bf16* w2p     = (bf16*)(SM + 150000);    // [64][800] permuted conv2 weights
    int*   cnt  = (int*)(SM + 256000);
    float* ScF  = SM + 256004;               // scratch region
    float* B0   = ScF + 32000000;
    bf16* wb_qkvd = (bf16*)B0;
    bf16* wb_f1   = (bf16*)(B0 + 2097152);
    bf16* wb_f2   = (bf16*)(B0 + 4194304);
    bf16* Erb     = (bf16*)(B0 + 6291456);
    bf16* xn_b    = (bf16*)(B0 + 6419456);
    bf16* AO_b    = (bf16*)(B0 + 7443456);
    bf16* Qb_b    = (bf16*)(B0 + 8467456);
    bf16* Kb_b    = (bf16*)(B0 + 9491456);
    bf16* Vb_b    = (bf16*)(B0 + 10515456);
    bf16* FFH_b   = (bf16*)(B0 + 11539456);
    bf16* Vt      = (bf16*)(B0 + 15635456);
    bf16* convout = (bf16*)(B0 + 16684032);  // pre-loop scratch [56000,64]

    hipMemsetAsync(cnt, 0, sizeof(int), stream);
    sniff_k<<<1024, 256, 0, stream>>>((const unsigned short*)d_in[20], 1000000, cnt);

    // compact fp32-copy table: only the tensors that actually get copied.
    static const int cvt_ids[NCVT] = {0, 1, 2, 4, 6, 7, 8, 13, 14, 15, 16,
                                      18, 19, 21, 23, 24, 25};
    CvtArgs ca;
    unsigned cum = 0;
    for (int t = 0; t < NCVT; t++) {
        int w = cvt_ids[t];
        ca.src[t] = d_in[w];
        ca.dst[t] = off[w];
        ca.cum[t] = cum;
        cum += off[w + 1] - off[w];
    }
    ca.cum[NCVT] = cum;   // 877,696
    ca.cnt = cnt; ca.dstA = A;
    cvt_all<<<(cum + 255) / 256, 256, 0, stream>>>(ca);

    // big weights: straight dtype-adaptive downcast from d_in
    for (int t = 0; t < 4; t++)
        f2bf_dyn<<<4096, 256, 0, stream>>>(d_in[9 + t], wb_qkvd + (size_t)t * 1048576,
                                           1048576, cnt);
    f2bf_dyn<<<16384, 256, 0, stream>>>(d_in[20], wb_f1, 4194304, cnt);
    f2bf_dyn<<<16384, 256, 0, stream>>>(d_in[22], wb_f2, 4194304, cnt);
    f2bf_dyn<<<1000,  256, 0, stream>>>(d_in[17], Erb,   256000, cnt);
    f2bf_dyn<<<128,   256, 0, stream>>>(d_in[5],  projw_b, 32768, cnt);
    w2perm<<<200, 256, 0, stream>>>(d_in[3], w2p, cnt);

    // conv frontend (implicit-GEMM conv2; no im2col)
    conv1_pool2<<<dim3(4, 14, 16), 256, 0, stream>>>(spec, c1w, c1b, P1c);
    conv2_gemm<<<dim3(16, 14, 4), 256, 0, stream>>>(P1c, w2p, c2b, convout);
    pool2_k<<<1000, 256, 0, stream>>>(convout, p2t_b);
    mfma_big<64, 64, 0, 0, false><<<dim3(63, 8), 256, 0, stream>>>(
        p2t_b, projw_b, projb, nullptr, x, nullptr, BT, DM, 64, 0, 0, 0);

    for (int l = 0; l < LL; l++) {
        layernorm_k<<<BT, 256, 0, stream>>>(x, ln1g + l * DM, ln1b + l * DM, xn_b);
        mfma_big<64, 128, 1, 0, true><<<dim3(63, 12), 256, 0, stream>>>(
            xn_b, wb_qkvd + (size_t)l * DM * DM, qb + l * DM, nullptr,
            nullptr, Qb_b, BT, 1536, DM, 1048576, 2048, 2048000);
        vt_k<<<dim3(16, 32), 256, 0, stream>>>(Vb_b, Vt);
        attn_fused<<<dim3(16, 1, 32), 256, 0, stream>>>(
            Qb_b, Kb_b, Erb + (size_t)l * TT * DEPTH, Vt, AO_b);
        mfma_big<64, 64, 0, 0, false><<<dim3(63, 8), 256, 0, stream>>>(
            AO_b, wb_qkvd + 3 * 1048576 + (size_t)l * DM * DM, db + l * DM, x,
            x, nullptr, BT, DM, DM, 0, 0, 0);
        layernorm_k<<<BT, 256, 0, stream>>>(x, ln2g + l * DM, ln2b + l * DM, xn_b);
        mfma_big<64, 128, 0, 1, true><<<dim3(63, 16), 256, 0, stream>>>(
            xn_b, wb_f1 + (size_t)l * FFN * DM, f1b + l * FFN, nullptr,
            nullptr, FFH_b, BT, FFN, DM, 0, 0, 0);
        mfma_big<64, 64, 0, 0, false><<<dim3(63, 8), 256, 0, stream>>>(
            FFH_b, wb_f2 + (size_t)l * DM * FFN, f2b_ + l * DM, x,
            x, nullptr, BT, DM, FFN, 0, 0, 0);
    }

    gemm_out<<<dim3(125, 4), 256, 0, stream>>>(x, depw, depb, cnt, d_out, BT, EDIM, DM);
}